// Round 7
// baseline (614.669 us; speedup 1.0000x reference)
//
#include <hip/hip_runtime.h>
#include <hip/hip_bf16.h>
#include <cstdio>

#define B     64
#define DIN   1024
#define NPRI  2048
#define DPRI  16
#define NCLS  25
#define DCLS  16
#define EMEPS 1e-6f
#define LNEPS 1e-5f
#define KS2   8
#define NCHUNK_S 16
#define NCHP  128

// ---------------- workspace layout (float offsets) ----------------
#define OFF_POSE 0                                   // poseT [NPRI*DPRI][B] f32
#define OFF_ZN   (OFF_POSE + NPRI*DPRI*B)            // [B][DIN]
#define OFF_ACTT (OFF_ZN + B*DIN)                    // [NPRI][B]
#define OFF_G2P  (OFF_ACTT + NPRI*B)                 // gemm2 partial [KS2][NPRI][B]
#define OFF_V    (OFF_G2P + KS2*NPRI*B)              // f16 [NPRI][NCLS][B][DCLS]
#define V_FLOATS (NPRI*NCLS*B*DCLS/2)
#define OFF_PART (OFF_V + V_FLOATS)                  // [NCLS][NCHP][33][B]
#define OFF_MU   (OFF_PART + NCLS*NCHP*33*B)         // [NCLS][DCLS][B]
#define OFF_MI4  (OFF_MU + NCLS*DCLS*B)              // float4 [NCLS][8][B]
#define OFF_BASE (OFF_MI4 + NCLS*8*B*4)              // [NCLS][B]
#define OFF_ZH   (OFF_BASE + NCLS*B)                 // fp16 z [B][DIN]
#define WS_FLOATS (OFF_ZH + B*DIN/2)

typedef __attribute__((ext_vector_type(8))) _Float16 f16x8;
typedef __attribute__((ext_vector_type(4))) float f32x4;

__device__ __forceinline__ unsigned pack_f16(float a, float b) {
  union { _Float16 h[2]; unsigned u; } x;
  x.h[0] = (_Float16)a; x.h[1] = (_Float16)b;
  return x.u;
}
__device__ __forceinline__ float f16lo(unsigned u) {
  union { unsigned u; _Float16 h[2]; } x; x.u = u; return (float)x.h[0];
}
__device__ __forceinline__ float f16hi(unsigned u) {
  union { unsigned u; _Float16 h[2]; } x; x.u = u; return (float)x.h[1];
}

// ---------------- LayerNorm + z->fp16 ----------------
__global__ __launch_bounds__(256) void k_lnzh(const float* __restrict__ z,
                                              const float* __restrict__ g,
                                              const float* __restrict__ bb,
                                              float* __restrict__ zn,
                                              unsigned* __restrict__ zh) {
  int row = blockIdx.x, t = threadIdx.x;
  const float* zr = z + row * DIN;
  float4 v = ((const float4*)zr)[t];
  // fp16 copy of raw z
  uint2 hz = {pack_f16(v.x, v.y), pack_f16(v.z, v.w)};
  *(uint2*)&zh[row * 512 + t * 2] = hz;
  float s  = v.x + v.y + v.z + v.w;
  float s2 = v.x*v.x + v.y*v.y + v.z*v.z + v.w*v.w;
  for (int off = 32; off; off >>= 1) {
    s  += __shfl_down(s, off);
    s2 += __shfl_down(s2, off);
  }
  __shared__ float ls[8];
  int wv = t >> 6, ln = t & 63;
  if (ln == 0) { ls[wv*2] = s; ls[wv*2+1] = s2; }
  __syncthreads();
  s  = ls[0] + ls[2] + ls[4] + ls[6];
  s2 = ls[1] + ls[3] + ls[5] + ls[7];
  float mean = s * (1.0f / DIN);
  float var  = s2 * (1.0f / DIN) - mean * mean;
  float inv  = 1.0f / sqrtf(var + LNEPS);
  float4 gg = ((const float4*)g)[t];
  float4 bv = ((const float4*)bb)[t];
  float4 o;
  o.x = (v.x - mean) * inv * gg.x + bv.x;
  o.y = (v.y - mean) * inv * gg.y + bv.y;
  o.z = (v.z - mean) * inv * gg.z + bv.z;
  o.w = (v.w - mean) * inv * gg.w + bv.w;
  ((float4*)(zn + row * DIN))[t] = o;
}

// ---------------- GEMM1 via fp16 MFMA, 8 waves, in-block k-split ----------------
__global__ __launch_bounds__(512) void k_gemm1m(const unsigned* __restrict__ zh,
                                                const float* __restrict__ w1,
                                                const float* __restrict__ b1,
                                                float* __restrict__ poseT) {
  __shared__ __align__(16) unsigned bt[2][64 * 68];
  __shared__ __align__(16) unsigned zl[2][64 * 68];
  int t = threadIdx.x;
  int c0 = blockIdx.x * 64;
  int l = t & 63, w = t >> 6;
  int kh = w >> 2, cw = w & 3;
  int c15 = l & 15, kq = l >> 4;
  int h  = t >> 8;
  int th = t & 255;
  int s_kp = th >> 2;
  int s_q  = th & 3;

  f32x4 acc0 = {0,0,0,0}, acc1 = {0,0,0,0}, acc2 = {0,0,0,0}, acc3 = {0,0,0,0};

  for (int it = 0; it < 4; ++it) {
    int k0 = (h * 4 + it) * 128;
#pragma unroll
    for (int u = 0; u < 4; ++u) {
      int cq = s_q + 4 * u;
      const float* src0 = w1 + (size_t)(k0 + 2 * s_kp) * 32768 + c0 + cq * 4;
      float4 r0 = *(const float4*)src0;
      float4 r1 = *(const float4*)(src0 + 32768);
      unsigned* dst = &bt[h][(cq * 4) * 68 + s_kp];
      dst[0]   = pack_f16(r0.x, r1.x);
      dst[68]  = pack_f16(r0.y, r1.y);
      dst[136] = pack_f16(r0.z, r1.z);
      dst[204] = pack_f16(r0.w, r1.w);
    }
#pragma unroll
    for (int u = 0; u < 4; ++u) {
      int ku4 = s_q + 4 * u;
      uint4 v = *(const uint4*)&zh[(size_t)s_kp * 512 + (k0 >> 1) + ku4 * 4];
      *(uint4*)&zl[h][s_kp * 68 + ku4 * 4] = v;
    }
    __syncthreads();
#pragma unroll
    for (int ks = 0; ks < 4; ++ks) {
      union { uint4 u; f16x8 hh; } bf, a0, a1, a2, a3;
      bf.u = *(const uint4*)&bt[kh][(cw * 16 + c15) * 68 + ks * 16 + kq * 4];
      a0.u = *(const uint4*)&zl[kh][(c15)      * 68 + ks * 16 + kq * 4];
      a1.u = *(const uint4*)&zl[kh][(16 + c15) * 68 + ks * 16 + kq * 4];
      a2.u = *(const uint4*)&zl[kh][(32 + c15) * 68 + ks * 16 + kq * 4];
      a3.u = *(const uint4*)&zl[kh][(48 + c15) * 68 + ks * 16 + kq * 4];
      acc0 = __builtin_amdgcn_mfma_f32_16x16x32_f16(a0.hh, bf.hh, acc0, 0, 0, 0);
      acc1 = __builtin_amdgcn_mfma_f32_16x16x32_f16(a1.hh, bf.hh, acc1, 0, 0, 0);
      acc2 = __builtin_amdgcn_mfma_f32_16x16x32_f16(a2.hh, bf.hh, acc2, 0, 0, 0);
      acc3 = __builtin_amdgcn_mfma_f32_16x16x32_f16(a3.hh, bf.hh, acc3, 0, 0, 0);
    }
    __syncthreads();
  }

  float* red = (float*)&zl[0][0];
  if (kh == 1) {
    int cc = cw * 16 + c15;
    *(float4*)&red[cc * 68 + kq * 4]      = *(float4*)&acc0;
    *(float4*)&red[cc * 68 + 16 + kq * 4] = *(float4*)&acc1;
    *(float4*)&red[cc * 68 + 32 + kq * 4] = *(float4*)&acc2;
    *(float4*)&red[cc * 68 + 48 + kq * 4] = *(float4*)&acc3;
  }
  __syncthreads();
  if (kh == 0) {
    int cc = cw * 16 + c15;
    int c = c0 + cc;
    float bc = b1[c];
    float4 r0 = *(float4*)&red[cc * 68 + kq * 4];
    float4 r1 = *(float4*)&red[cc * 68 + 16 + kq * 4];
    float4 r2 = *(float4*)&red[cc * 68 + 32 + kq * 4];
    float4 r3 = *(float4*)&red[cc * 68 + 48 + kq * 4];
    float* pdst = poseT + (size_t)c * 64 + kq * 4;
    float4 o0 = {acc0[0] + r0.x + bc, acc0[1] + r0.y + bc, acc0[2] + r0.z + bc, acc0[3] + r0.w + bc};
    float4 o1 = {acc1[0] + r1.x + bc, acc1[1] + r1.y + bc, acc1[2] + r1.z + bc, acc1[3] + r1.w + bc};
    float4 o2 = {acc2[0] + r2.x + bc, acc2[1] + r2.y + bc, acc2[2] + r2.z + bc, acc2[3] + r2.w + bc};
    float4 o3 = {acc3[0] + r3.x + bc, acc3[1] + r3.y + bc, acc3[2] + r3.z + bc, acc3[3] + r3.w + bc};
    *(float4*)&pdst[0]  = o0;
    *(float4*)&pdst[16] = o1;
    *(float4*)&pdst[32] = o2;
    *(float4*)&pdst[48] = o3;
  }
}

// ---------------- GEMM2 k-split partial ----------------
__global__ __launch_bounds__(256, 2) void k_gemm2p(const float* __restrict__ zn,
                                                   const float* __restrict__ w2,
                                                   float* __restrict__ part) {
  __shared__ __align__(16) float znT[128 * 68];
  __shared__ __align__(16) float wl[128 * 68];
  int t = threadIdx.x;
  int c0 = blockIdx.x * 64;
  int k0 = blockIdx.y * 128;
  int zr_ = t >> 2, za = t & 3;
  int wk = t >> 1, wc = (t & 1) * 32;

#pragma unroll
  for (int jj = 0; jj < 4; ++jj) {
    int kb = za * 8 + jj * 32;
    const float* src = zn + zr_ * DIN + k0 + kb;
    float4 v0 = *(const float4*)src;
    float4 v1 = *(const float4*)(src + 4);
    znT[(kb+0)*68 + zr_] = v0.x; znT[(kb+1)*68 + zr_] = v0.y;
    znT[(kb+2)*68 + zr_] = v0.z; znT[(kb+3)*68 + zr_] = v0.w;
    znT[(kb+4)*68 + zr_] = v1.x; znT[(kb+5)*68 + zr_] = v1.y;
    znT[(kb+6)*68 + zr_] = v1.z; znT[(kb+7)*68 + zr_] = v1.w;
  }
  const float* wsrc = w2 + (size_t)(k0 + wk) * NPRI + c0 + wc;
#pragma unroll
  for (int j = 0; j < 8; ++j)
    *(float4*)&wl[wk * 68 + wc + j * 4] = *(const float4*)(wsrc + j * 4);
  __syncthreads();

  int r0 = (t >> 4) * 4, c0l = (t & 15) * 4;
  float acc[4][4];
#pragma unroll
  for (int j = 0; j < 4; ++j)
#pragma unroll
    for (int i = 0; i < 4; ++i) acc[j][i] = 0.f;

#pragma unroll 4
  for (int k = 0; k < 128; ++k) {
    float4 z4 = *(const float4*)&znT[k * 68 + r0];
    float4 w4 = *(const float4*)&wl[k * 68 + c0l];
    float zz[4] = {z4.x, z4.y, z4.z, z4.w};
    float ww[4] = {w4.x, w4.y, w4.z, w4.w};
#pragma unroll
    for (int j = 0; j < 4; ++j)
#pragma unroll
      for (int i = 0; i < 4; ++i) acc[j][i] += ww[j] * zz[i];
  }
  float* pdst = part + ((size_t)blockIdx.y * NPRI + c0 + c0l) * 64 + r0;
#pragma unroll
  for (int j = 0; j < 4; ++j) {
    float4 o = {acc[j][0], acc[j][1], acc[j][2], acc[j][3]};
    *(float4*)&pdst[j * 64] = o;
  }
}

__global__ __launch_bounds__(256) void k_gemm2r(const float* __restrict__ part,
                                                const float* __restrict__ b2,
                                                float* __restrict__ actt) {
  int idx = blockIdx.x * 256 + threadIdx.x;
  float4 s = {0.f, 0.f, 0.f, 0.f};
#pragma unroll
  for (int kz = 0; kz < KS2; ++kz) {
    float4 v = *(const float4*)&part[(size_t)kz * NPRI * 64 + idx * 4];
    s.x += v.x; s.y += v.y; s.z += v.z; s.w += v.w;
  }
  int c = (idx * 4) >> 6;
  float bc = b2[c];
  float4 o;
  o.x = fminf(fmaxf(1.0f / (1.0f + expf(-(s.x + bc))), 0.0f), 1.0f);
  o.y = fminf(fmaxf(1.0f / (1.0f + expf(-(s.y + bc))), 0.0f), 1.0f);
  o.z = fminf(fmaxf(1.0f / (1.0f + expf(-(s.z + bc))), 0.0f), 1.0f);
  o.w = fminf(fmaxf(1.0f / (1.0f + expf(-(s.w + bc))), 0.0f), 1.0f);
  *(float4*)&actt[idx * 4] = o;
}

// ---------------- votes: V[n][o][b][d] (f16) ----------------
__global__ __launch_bounds__(256) void k_votes(const float* __restrict__ poseT,
                                               const float* __restrict__ wcaps,
                                               unsigned* __restrict__ V) {
  __shared__ __align__(16) float wl[6400];
  __shared__ __align__(16) float pl[64 * 16];
  int n = blockIdx.x, t = threadIdx.x;
  const float* wsrc = wcaps + (size_t)n * 6400;
  for (int idx = t * 4; idx < 6400; idx += 1024)
    *(float4*)(wl + idx) = *(const float4*)(wsrc + idx);
  {
    float4 v = *(const float4*)(poseT + n * 1024 + t * 4);
    int i = (t * 4) >> 6, b = (t * 4) & 63;
    pl[(b+0)*16 + i] = v.x; pl[(b+1)*16 + i] = v.y;
    pl[(b+2)*16 + i] = v.z; pl[(b+3)*16 + i] = v.w;
  }
  __syncthreads();
  if (t >= 200) return;
  int o = t / 8, d0 = (t % 8) * 2;
  float w0[16], w1_[16];
#pragma unroll
  for (int i = 0; i < 16; ++i) {
    w0[i]  = wl[(i * 25 + o) * 16 + d0];
    w1_[i] = wl[(i * 25 + o) * 16 + d0 + 1];
  }
  unsigned* vd = V + (((size_t)n * 25 + o) * 64 * 16 + d0) / 2;
  for (int b = 0; b < 64; ++b) {
    const float* pb = &pl[b * 16];
    float a0 = 0.f, a1 = 0.f;
#pragma unroll
    for (int i = 0; i < 16; ++i) {
      float p = pb[i];
      a0 += p * w0[i];
      a1 += p * w1_[i];
    }
    vd[b * 8] = pack_f16(a0, a1);
  }
}

// ---------------- iteration-1 stats (uniform R) ----------------
__global__ __launch_bounds__(256) void k_stats1(const unsigned* __restrict__ V,
                                                const float* __restrict__ actt,
                                                float* __restrict__ part) {
  int o = blockIdx.y;
  int t = threadIdx.x, b = t & 63, wv = t >> 6;
  float S0 = 0.f, S1[16], S2[16];
#pragma unroll
  for (int d = 0; d < 16; ++d) { S1[d] = 0.f; S2[d] = 0.f; }
  int n0 = blockIdx.x * 128 + wv * 32;
  for (int k = 0; k < 32; ++k) {
    int n = n0 + k;
    float r = actt[n * 64 + b] * (1.0f / 25.0f);
    const uint4* vp = (const uint4*)(V + (((size_t)n * 25 + o) * 64 + b) * 8);
    uint4 u0 = vp[0], u1 = vp[1];
    unsigned uu[8] = {u0.x, u0.y, u0.z, u0.w, u1.x, u1.y, u1.z, u1.w};
    S0 += r;
#pragma unroll
    for (int q = 0; q < 8; ++q) {
      float v0 = f16lo(uu[q]), v1 = f16hi(uu[q]);
      float t0 = r * v0, t1 = r * v1;
      S1[2*q]   += t0;          S1[2*q+1] += t1;
      S2[2*q]   += t0 * v0;     S2[2*q+1] += t1 * v1;
    }
  }
  __shared__ float red[4 * 33 * 64];
  red[(wv * 33 + 0) * 64 + b] = S0;
#pragma unroll
  for (int d = 0; d < 16; ++d) {
    red[(wv * 33 + 1 + d) * 64 + b]  = S1[d];
    red[(wv * 33 + 17 + d) * 64 + b] = S2[d];
  }
  __syncthreads();
  if (wv == 0) {
    for (int s = 0; s < 33; ++s) {
      float tot = red[s * 64 + b] + red[(33 + s) * 64 + b] +
                  red[(66 + s) * 64 + b] + red[(99 + s) * 64 + b];
      part[((o * NCHUNK_S + blockIdx.x) * 33 + s) * 64 + b] = tot;
    }
  }
}

// ---------------- fused E+M step (iterations 2,3): one V pass ----------------
// grid (NCHP=128 n-chunks, 2 b-halves); 512 thr = 8 waves.
// lane l: dp = l>>3 (owns d=2dp,2dp+1), bl = l&7; wave w: ns = w>>2, b = bh*32+(w&3)*8+bl.
__global__ __launch_bounds__(512, 2) void k_emstep(const unsigned* __restrict__ V,
                                                   const float* __restrict__ actt,
                                                   const float* __restrict__ mi4,
                                                   const float* __restrict__ basew,
                                                   float* __restrict__ part) {
  __shared__ float comb[25 * 33 * 32];   // 105.6 KB
  int t = threadIdx.x;
  int l = t & 63, w = t >> 6;
  int dp = l >> 3, bl = l & 7;
  int ns = w >> 2;
  int b32 = (w & 3) * 8 + bl;
  int b = blockIdx.y * 32 + b32;
  int chunk = blockIdx.x;
  int n0 = chunk * 16 + ns * 8;

  float S0[25], S1a[25], S1b[25], S2a[25], S2b[25];
#pragma unroll
  for (int o = 0; o < 25; ++o) { S0[o]=0.f; S1a[o]=0.f; S1b[o]=0.f; S2a[o]=0.f; S2b[o]=0.f; }

  for (int i = 0; i < 8; ++i) {
    int n = n0 + i;
    float a = actt[n * 64 + b];
    unsigned v[25];
    float ql[25];
#pragma unroll
    for (int o = 0; o < 25; ++o)
      v[o] = V[(((size_t)n * 25 + o) * 64 + b) * 8 + dp];
#pragma unroll
    for (int o = 0; o < 25; ++o) {
      float4 mi = *(const float4*)&mi4[((o * 8 + dp) * 64 + b) * 4];
      float d0 = f16lo(v[o]) - mi.x;
      float d1 = f16hi(v[o]) - mi.z;
      ql[o] = d0 * d0 * mi.y + d1 * d1 * mi.w;
    }
    // reduce quadratic across the 8 dp lanes (strides 8,16,32)
#pragma unroll
    for (int o = 0; o < 25; ++o) {
      ql[o] += __shfl_xor(ql[o], 8);
      ql[o] += __shfl_xor(ql[o], 16);
      ql[o] += __shfl_xor(ql[o], 32);
    }
    float mx = -1e30f;
#pragma unroll
    for (int o = 0; o < 25; ++o) {
      ql[o] = basew[o * 64 + b] - 0.5f * ql[o];
      mx = fmaxf(mx, ql[o]);
    }
    float s = 0.f;
#pragma unroll
    for (int o = 0; o < 25; ++o) { ql[o] = expf(ql[o] - mx); s += ql[o]; }
    float rs = a / s;
#pragma unroll
    for (int o = 0; o < 25; ++o) {
      float r = ql[o] * rs;
      float v0 = f16lo(v[o]), v1 = f16hi(v[o]);
      float t0 = r * v0, t1 = r * v1;
      S0[o] += r;
      S1a[o] += t0;      S1b[o] += t1;
      S2a[o] += t0 * v0; S2b[o] += t1 * v1;
    }
  }
  // combine the two n-streams: ns=1 -> LDS, ns=0 adds and stores
  if (ns == 1) {
#pragma unroll
    for (int o = 0; o < 25; ++o) {
      if (dp == 0) comb[(o * 33 + 0) * 32 + b32] = S0[o];
      comb[(o * 33 + 1 + 2*dp) * 32 + b32]  = S1a[o];
      comb[(o * 33 + 2 + 2*dp) * 32 + b32]  = S1b[o];
      comb[(o * 33 + 17 + 2*dp) * 32 + b32] = S2a[o];
      comb[(o * 33 + 18 + 2*dp) * 32 + b32] = S2b[o];
    }
  }
  __syncthreads();
  if (ns == 0) {
#pragma unroll
    for (int o = 0; o < 25; ++o) {
      float* pp = part + ((size_t)(o * NCHP + chunk) * 33) * 64;
      if (dp == 0)
        pp[0 * 64 + b] = S0[o] + comb[(o * 33 + 0) * 32 + b32];
      pp[(1 + 2*dp) * 64 + b]  = S1a[o] + comb[(o * 33 + 1 + 2*dp) * 32 + b32];
      pp[(2 + 2*dp) * 64 + b]  = S1b[o] + comb[(o * 33 + 2 + 2*dp) * 32 + b32];
      pp[(17 + 2*dp) * 64 + b] = S2a[o] + comb[(o * 33 + 17 + 2*dp) * 32 + b32];
      pp[(18 + 2*dp) * 64 + b] = S2b[o] + comb[(o * 33 + 18 + 2*dp) * 32 + b32];
    }
  }
}

// ---------------- merged reduce + finish ----------------
template <int CH>
__global__ __launch_bounds__(256) void k_redfin(const float* __restrict__ part,
                                                const float* __restrict__ beta_u,
                                                const float* __restrict__ beta_a,
                                                float* __restrict__ mu,
                                                float* __restrict__ mi4,
                                                float* __restrict__ basew) {
  __shared__ float st[33 * 64];
  int o = blockIdx.x, t = threadIdx.x;
  for (int slot = t; slot < 33 * 64; slot += 256) {
    float s = 0.f;
    const float* pp = part + (size_t)o * CH * 2112 + slot;
    for (int c = 0; c < CH; ++c) s += pp[(size_t)c * 2112];
    st[slot] = s;
  }
  __syncthreads();
  if (t < 64) {
    int b = t;
    float s0 = st[b];
    float rsm = s0 + EMEPS;
    float inv_rs = 1.0f / rsm;
    float ldet = 0.f;
    float mloc[16], iloc[16];
#pragma unroll
    for (int d = 0; d < 16; ++d) {
      float s1 = st[(1 + d) * 64 + b];
      float s2 = st[(17 + d) * 64 + b];
      float m = s1 * inv_rs;
      float var = (s2 - 2.0f * m * s1 + m * m * s0) * inv_rs;
      float sg = fmaxf(var, 0.0f) + EMEPS;
      mloc[d] = m;
      iloc[d] = 1.0f / sg;
      mu[(o * 16 + d) * 64 + b] = m;
      ldet += logf(sg);
    }
#pragma unroll
    for (int q = 0; q < 8; ++q) {
      float4 v = {mloc[2*q], iloc[2*q], mloc[2*q+1], iloc[2*q+1]};
      *(float4*)&mi4[((o * 8 + q) * 64 + b) * 4] = v;
    }
    float cost = (16.0f * beta_u[o] + 0.5f * ldet) * rsm;
    float x = beta_a[o] - cost;
    float a = 1.0f / (1.0f + expf(-x));
    basew[o * 64 + b] = logf(a + EMEPS) - 0.5f * ldet;
  }
}

// ---------------- final E-step -> q ----------------
__global__ __launch_bounds__(256) void k_estepq(const unsigned* __restrict__ V,
                                                const float* __restrict__ mi4,
                                                const float* __restrict__ basew,
                                                float* __restrict__ qout) {
  int t = threadIdx.x, b = t & 63, ng = t >> 6;
  int n = blockIdx.x * 4 + ng;
  float l[25];
  float mx = -1e30f;
#pragma unroll
  for (int o = 0; o < 25; ++o) {
    const uint4* vp = (const uint4*)(V + (((size_t)n * 25 + o) * 64 + b) * 8);
    uint4 u0 = vp[0], u1 = vp[1];
    unsigned uu[8] = {u0.x, u0.y, u0.z, u0.w, u1.x, u1.y, u1.z, u1.w};
    float acc = 0.f;
#pragma unroll
    for (int qq = 0; qq < 8; ++qq) {
      float4 mi = *(const float4*)&mi4[((o * 8 + qq) * 64 + b) * 4];
      float d0 = f16lo(uu[qq]) - mi.x;
      float d1 = f16hi(uu[qq]) - mi.z;
      acc += d0 * d0 * mi.y + d1 * d1 * mi.w;
    }
    l[o] = basew[o * 64 + b] - 0.5f * acc;
    mx = fmaxf(mx, l[o]);
  }
  float s = 0.f;
#pragma unroll
  for (int o = 0; o < 25; ++o) { l[o] = expf(l[o] - mx); s += l[o]; }
  float inv = 1.0f / s;
  float* qp = qout + ((size_t)b * NPRI + n) * 25;
#pragma unroll
  for (int o = 0; o < 25; ++o) qp[o] = l[o] * inv;
}

// ---------------- epilogue ----------------
__global__ __launch_bounds__(64) void k_out(const float* __restrict__ mu,
                                            const float* __restrict__ g2,
                                            const float* __restrict__ bb2,
                                            const float* __restrict__ w3,
                                            const float* __restrict__ b3,
                                            float* __restrict__ out) {
  int o = blockIdx.x, b = threadIdx.x;
  float m[16];
  float s = 0.f;
#pragma unroll
  for (int d = 0; d < 16; ++d) { m[d] = mu[(o * 16 + d) * 64 + b]; s += m[d]; }
  float mean = s * (1.0f / 16.0f);
  float var = 0.f;
#pragma unroll
  for (int d = 0; d < 16; ++d) { float dd = m[d] - mean; var += dd * dd; }
  var *= (1.0f / 16.0f);
  float inv = 1.0f / sqrtf(var + LNEPS);
  float logit = 0.f, nrm = 0.f;
#pragma unroll
  for (int d = 0; d < 16; ++d) {
    float nh = (m[d] - mean) * inv * g2[d] + bb2[d];
    logit += nh * w3[d];
    nrm += m[d] * m[d];
  }
  out[b * 25 + o] = logit + b3[0];
  out[1600 + b * 25 + o] = sqrtf(nrm);
  float* pp = out + 3200 + (b * 25 + o) * 16;
#pragma unroll
  for (int d = 0; d < 16; ++d) pp[d] = m[d];
}

extern "C" void kernel_launch(void* const* d_in, const int* in_sizes, int n_in,
                              void* d_out, int out_size, void* d_ws, size_t ws_size,
                              hipStream_t stream) {
  const float* z      = (const float*)d_in[0];
  const float* w1     = (const float*)d_in[1];
  const float* b1     = (const float*)d_in[2];
  const float* ln1g   = (const float*)d_in[3];
  const float* ln1b   = (const float*)d_in[4];
  const float* w2     = (const float*)d_in[5];
  const float* b2     = (const float*)d_in[6];
  const float* wcaps  = (const float*)d_in[7];
  const float* beta_u = (const float*)d_in[8];
  const float* beta_a = (const float*)d_in[9];
  const float* ln2g   = (const float*)d_in[10];
  const float* ln2b   = (const float*)d_in[11];
  const float* w3     = (const float*)d_in[12];
  const float* b3     = (const float*)d_in[13];

  if (ws_size < (size_t)WS_FLOATS * 4) {
    fprintf(stderr, "kernel_launch: ws too small: %zu < %zu bytes\n",
            ws_size, (size_t)WS_FLOATS * 4);
  }

  float* ws    = (float*)d_ws;
  float* out   = (float*)d_out;
  float* poseT = ws + OFF_POSE;
  float* zn    = ws + OFF_ZN;
  float* actt  = ws + OFF_ACTT;
  float* g2p   = ws + OFF_G2P;
  unsigned* V  = (unsigned*)(ws + OFF_V);
  float* part  = ws + OFF_PART;
  float* muw   = ws + OFF_MU;
  float* mi4   = ws + OFF_MI4;
  float* bse   = ws + OFF_BASE;
  unsigned* zh = (unsigned*)(ws + OFF_ZH);

  k_lnzh<<<64, 256, 0, stream>>>(z, ln1g, ln1b, zn, zh);
  k_gemm1m<<<512, 512, 0, stream>>>(zh, w1, b1, poseT);
  k_gemm2p<<<dim3(32, KS2), 256, 0, stream>>>(zn, w2, g2p);
  k_gemm2r<<<128, 256, 0, stream>>>(g2p, b2, actt);
  k_votes<<<2048, 256, 0, stream>>>(poseT, wcaps, V);

  // iteration 1 (uniform R)
  k_stats1<<<dim3(NCHUNK_S, 25), 256, 0, stream>>>(V, actt, part);
  k_redfin<NCHUNK_S><<<25, 256, 0, stream>>>(part, beta_u, beta_a, muw, mi4, bse);

  // iterations 2,3 — fused E+M, single V pass each
  for (int it = 0; it < 2; ++it) {
    k_emstep<<<dim3(NCHP, 2), 512, 0, stream>>>(V, actt, mi4, bse, part);
    k_redfin<NCHP><<<25, 256, 0, stream>>>(part, beta_u, beta_a, muw, mi4, bse);
  }

  // final E-step -> q, then outputs
  k_estepq<<<512, 256, 0, stream>>>(V, mi4, bse, out + 28800);
  k_out<<<25, 64, 0, stream>>>(muw, ln2g, ln2b, w3, b3, out);
}

// Round 8
// 381.218 us; speedup vs baseline: 1.6124x; 1.6124x over previous
//
#include <hip/hip_runtime.h>
#include <hip/hip_bf16.h>
#include <cstdio>

#define B     64
#define DIN   1024
#define NPRI  2048
#define DPRI  16
#define NCLS  25
#define DCLS  16
#define EMEPS 1e-6f
#define LNEPS 1e-5f
#define KS2   8
#define NCH   32

// ---------------- workspace layout (float offsets) ----------------
#define OFF_POSE 0                                   // poseT [NPRI*DPRI][B] f32
#define OFF_ZN   (OFF_POSE + NPRI*DPRI*B)            // [B][DIN]
#define OFF_ACTT (OFF_ZN + B*DIN)                    // [NPRI][B]
#define OFF_G2P  (OFF_ACTT + NPRI*B)                 // gemm2 partial [KS2][NPRI][B]
#define OFF_V    (OFF_G2P + KS2*NPRI*B)              // f16 [NPRI][NCLS][B][DCLS]
#define V_FLOATS (NPRI*NCLS*B*DCLS/2)
#define OFF_R    (OFF_V + V_FLOATS)                  // f16 [NPRI][NCLS][B]
#define R_FLOATS (NPRI*NCLS*B/2)
#define OFF_PART (OFF_R + R_FLOATS)                  // [NCLS][NCH][33][B]
#define OFF_MU   (OFF_PART + NCLS*NCH*33*B)          // [NCLS][DCLS][B]
#define OFF_MI4  (OFF_MU + NCLS*DCLS*B)              // float4 [NCLS][8][B]
#define OFF_BASE (OFF_MI4 + NCLS*8*B*4)              // [NCLS][B]
#define OFF_ZH   (OFF_BASE + NCLS*B)                 // fp16 z [B][DIN]
#define WS_FLOATS (OFF_ZH + B*DIN/2)

typedef __attribute__((ext_vector_type(8))) _Float16 f16x8;
typedef __attribute__((ext_vector_type(4))) float f32x4;

__device__ __forceinline__ unsigned pack_f16(float a, float b) {
  union { _Float16 h[2]; unsigned u; } x;
  x.h[0] = (_Float16)a; x.h[1] = (_Float16)b;
  return x.u;
}
__device__ __forceinline__ float f16lo(unsigned u) {
  union { unsigned u; _Float16 h[2]; } x; x.u = u; return (float)x.h[0];
}
__device__ __forceinline__ float f16hi(unsigned u) {
  union { unsigned u; _Float16 h[2]; } x; x.u = u; return (float)x.h[1];
}
__device__ __forceinline__ unsigned short f16bits(float a) {
  union { _Float16 h; unsigned short u; } x; x.h = (_Float16)a; return x.u;
}
__device__ __forceinline__ float f16val(unsigned short u) {
  union { unsigned short u; _Float16 h; } x; x.u = u; return (float)x.h;
}

// ---------------- LayerNorm + z->fp16 ----------------
__global__ __launch_bounds__(256) void k_lnzh(const float* __restrict__ z,
                                              const float* __restrict__ g,
                                              const float* __restrict__ bb,
                                              float* __restrict__ zn,
                                              unsigned* __restrict__ zh) {
  int row = blockIdx.x, t = threadIdx.x;
  const float* zr = z + row * DIN;
  float4 v = ((const float4*)zr)[t];
  uint2 hz = {pack_f16(v.x, v.y), pack_f16(v.z, v.w)};
  *(uint2*)&zh[row * 512 + t * 2] = hz;
  float s  = v.x + v.y + v.z + v.w;
  float s2 = v.x*v.x + v.y*v.y + v.z*v.z + v.w*v.w;
  for (int off = 32; off; off >>= 1) {
    s  += __shfl_down(s, off);
    s2 += __shfl_down(s2, off);
  }
  __shared__ float ls[8];
  int wv = t >> 6, ln = t & 63;
  if (ln == 0) { ls[wv*2] = s; ls[wv*2+1] = s2; }
  __syncthreads();
  s  = ls[0] + ls[2] + ls[4] + ls[6];
  s2 = ls[1] + ls[3] + ls[5] + ls[7];
  float mean = s * (1.0f / DIN);
  float var  = s2 * (1.0f / DIN) - mean * mean;
  float inv  = 1.0f / sqrtf(var + LNEPS);
  float4 gg = ((const float4*)g)[t];
  float4 bv = ((const float4*)bb)[t];
  float4 o;
  o.x = (v.x - mean) * inv * gg.x + bv.x;
  o.y = (v.y - mean) * inv * gg.y + bv.y;
  o.z = (v.z - mean) * inv * gg.z + bv.z;
  o.w = (v.w - mean) * inv * gg.w + bv.w;
  ((float4*)(zn + row * DIN))[t] = o;
}

// ---------------- GEMM1 via fp16 MFMA, 8 waves, in-block k-split, reg-prefetch ----------------
__global__ __launch_bounds__(512) void k_gemm1m(const unsigned* __restrict__ zh,
                                                const float* __restrict__ w1,
                                                const float* __restrict__ b1,
                                                float* __restrict__ poseT) {
  __shared__ __align__(16) unsigned bt[2][64 * 68];
  __shared__ __align__(16) unsigned zl[2][64 * 68];
  int t = threadIdx.x;
  int c0 = blockIdx.x * 64;
  int l = t & 63, w = t >> 6;
  int kh = w >> 2, cw = w & 3;
  int c15 = l & 15, kq = l >> 4;
  int h  = t >> 8;
  int th = t & 255;
  int s_kp = th >> 2;
  int s_q  = th & 3;

  f32x4 acc0 = {0,0,0,0}, acc1 = {0,0,0,0}, acc2 = {0,0,0,0}, acc3 = {0,0,0,0};

  float4 wr0[4], wr1[4];
  uint4  zr4[4];
  // prologue: load chunk 0 of this half
  {
    int k0 = h * 512;
#pragma unroll
    for (int u = 0; u < 4; ++u) {
      int cq = s_q + 4 * u;
      const float* src0 = w1 + (size_t)(k0 + 2 * s_kp) * 32768 + c0 + cq * 4;
      wr0[u] = *(const float4*)src0;
      wr1[u] = *(const float4*)(src0 + 32768);
      zr4[u] = *(const uint4*)&zh[(size_t)s_kp * 512 + (k0 >> 1) + cq * 4];
    }
  }

  for (int it = 0; it < 4; ++it) {
    // write staged registers to LDS
#pragma unroll
    for (int u = 0; u < 4; ++u) {
      int cq = s_q + 4 * u;
      unsigned* dst = &bt[h][(cq * 4) * 68 + s_kp];
      dst[0]   = pack_f16(wr0[u].x, wr1[u].x);
      dst[68]  = pack_f16(wr0[u].y, wr1[u].y);
      dst[136] = pack_f16(wr0[u].z, wr1[u].z);
      dst[204] = pack_f16(wr0[u].w, wr1[u].w);
      *(uint4*)&zl[h][s_kp * 68 + cq * 4] = zr4[u];
    }
    __syncthreads();
    // prefetch next chunk while MFMA runs
    if (it < 3) {
      int k0n = (h * 4 + it + 1) * 128;
#pragma unroll
      for (int u = 0; u < 4; ++u) {
        int cq = s_q + 4 * u;
        const float* src0 = w1 + (size_t)(k0n + 2 * s_kp) * 32768 + c0 + cq * 4;
        wr0[u] = *(const float4*)src0;
        wr1[u] = *(const float4*)(src0 + 32768);
        zr4[u] = *(const uint4*)&zh[(size_t)s_kp * 512 + (k0n >> 1) + cq * 4];
      }
    }
#pragma unroll
    for (int ks = 0; ks < 4; ++ks) {
      union { uint4 u; f16x8 hh; } bf, a0, a1, a2, a3;
      bf.u = *(const uint4*)&bt[kh][(cw * 16 + c15) * 68 + ks * 16 + kq * 4];
      a0.u = *(const uint4*)&zl[kh][(c15)      * 68 + ks * 16 + kq * 4];
      a1.u = *(const uint4*)&zl[kh][(16 + c15) * 68 + ks * 16 + kq * 4];
      a2.u = *(const uint4*)&zl[kh][(32 + c15) * 68 + ks * 16 + kq * 4];
      a3.u = *(const uint4*)&zl[kh][(48 + c15) * 68 + ks * 16 + kq * 4];
      acc0 = __builtin_amdgcn_mfma_f32_16x16x32_f16(a0.hh, bf.hh, acc0, 0, 0, 0);
      acc1 = __builtin_amdgcn_mfma_f32_16x16x32_f16(a1.hh, bf.hh, acc1, 0, 0, 0);
      acc2 = __builtin_amdgcn_mfma_f32_16x16x32_f16(a2.hh, bf.hh, acc2, 0, 0, 0);
      acc3 = __builtin_amdgcn_mfma_f32_16x16x32_f16(a3.hh, bf.hh, acc3, 0, 0, 0);
    }
    __syncthreads();
  }

  float* red = (float*)&zl[0][0];
  if (kh == 1) {
    int cc = cw * 16 + c15;
    *(float4*)&red[cc * 68 + kq * 4]      = *(float4*)&acc0;
    *(float4*)&red[cc * 68 + 16 + kq * 4] = *(float4*)&acc1;
    *(float4*)&red[cc * 68 + 32 + kq * 4] = *(float4*)&acc2;
    *(float4*)&red[cc * 68 + 48 + kq * 4] = *(float4*)&acc3;
  }
  __syncthreads();
  if (kh == 0) {
    int cc = cw * 16 + c15;
    int c = c0 + cc;
    float bc = b1[c];
    float4 r0 = *(float4*)&red[cc * 68 + kq * 4];
    float4 r1 = *(float4*)&red[cc * 68 + 16 + kq * 4];
    float4 r2 = *(float4*)&red[cc * 68 + 32 + kq * 4];
    float4 r3 = *(float4*)&red[cc * 68 + 48 + kq * 4];
    float* pdst = poseT + (size_t)c * 64 + kq * 4;
    float4 o0 = {acc0[0] + r0.x + bc, acc0[1] + r0.y + bc, acc0[2] + r0.z + bc, acc0[3] + r0.w + bc};
    float4 o1 = {acc1[0] + r1.x + bc, acc1[1] + r1.y + bc, acc1[2] + r1.z + bc, acc1[3] + r1.w + bc};
    float4 o2 = {acc2[0] + r2.x + bc, acc2[1] + r2.y + bc, acc2[2] + r2.z + bc, acc2[3] + r2.w + bc};
    float4 o3 = {acc3[0] + r3.x + bc, acc3[1] + r3.y + bc, acc3[2] + r3.z + bc, acc3[3] + r3.w + bc};
    *(float4*)&pdst[0]  = o0;
    *(float4*)&pdst[16] = o1;
    *(float4*)&pdst[32] = o2;
    *(float4*)&pdst[48] = o3;
  }
}

// ---------------- GEMM2 k-split partial ----------------
__global__ __launch_bounds__(256, 2) void k_gemm2p(const float* __restrict__ zn,
                                                   const float* __restrict__ w2,
                                                   float* __restrict__ part) {
  __shared__ __align__(16) float znT[128 * 68];
  __shared__ __align__(16) float wl[128 * 68];
  int t = threadIdx.x;
  int c0 = blockIdx.x * 64;
  int k0 = blockIdx.y * 128;
  int zr_ = t >> 2, za = t & 3;
  int wk = t >> 1, wc = (t & 1) * 32;

#pragma unroll
  for (int jj = 0; jj < 4; ++jj) {
    int kb = za * 8 + jj * 32;
    const float* src = zn + zr_ * DIN + k0 + kb;
    float4 v0 = *(const float4*)src;
    float4 v1 = *(const float4*)(src + 4);
    znT[(kb+0)*68 + zr_] = v0.x; znT[(kb+1)*68 + zr_] = v0.y;
    znT[(kb+2)*68 + zr_] = v0.z; znT[(kb+3)*68 + zr_] = v0.w;
    znT[(kb+4)*68 + zr_] = v1.x; znT[(kb+5)*68 + zr_] = v1.y;
    znT[(kb+6)*68 + zr_] = v1.z; znT[(kb+7)*68 + zr_] = v1.w;
  }
  const float* wsrc = w2 + (size_t)(k0 + wk) * NPRI + c0 + wc;
#pragma unroll
  for (int j = 0; j < 8; ++j)
    *(float4*)&wl[wk * 68 + wc + j * 4] = *(const float4*)(wsrc + j * 4);
  __syncthreads();

  int r0 = (t >> 4) * 4, c0l = (t & 15) * 4;
  float acc[4][4];
#pragma unroll
  for (int j = 0; j < 4; ++j)
#pragma unroll
    for (int i = 0; i < 4; ++i) acc[j][i] = 0.f;

#pragma unroll 4
  for (int k = 0; k < 128; ++k) {
    float4 z4 = *(const float4*)&znT[k * 68 + r0];
    float4 w4 = *(const float4*)&wl[k * 68 + c0l];
    float zz[4] = {z4.x, z4.y, z4.z, z4.w};
    float ww[4] = {w4.x, w4.y, w4.z, w4.w};
#pragma unroll
    for (int j = 0; j < 4; ++j)
#pragma unroll
      for (int i = 0; i < 4; ++i) acc[j][i] += ww[j] * zz[i];
  }
  float* pdst = part + ((size_t)blockIdx.y * NPRI + c0 + c0l) * 64 + r0;
#pragma unroll
  for (int j = 0; j < 4; ++j) {
    float4 o = {acc[j][0], acc[j][1], acc[j][2], acc[j][3]};
    *(float4*)&pdst[j * 64] = o;
  }
}

__global__ __launch_bounds__(256) void k_gemm2r(const float* __restrict__ part,
                                                const float* __restrict__ b2,
                                                float* __restrict__ actt) {
  int idx = blockIdx.x * 256 + threadIdx.x;
  float4 s = {0.f, 0.f, 0.f, 0.f};
#pragma unroll
  for (int kz = 0; kz < KS2; ++kz) {
    float4 v = *(const float4*)&part[(size_t)kz * NPRI * 64 + idx * 4];
    s.x += v.x; s.y += v.y; s.z += v.z; s.w += v.w;
  }
  int c = (idx * 4) >> 6;
  float bc = b2[c];
  float4 o;
  o.x = fminf(fmaxf(1.0f / (1.0f + expf(-(s.x + bc))), 0.0f), 1.0f);
  o.y = fminf(fmaxf(1.0f / (1.0f + expf(-(s.y + bc))), 0.0f), 1.0f);
  o.z = fminf(fmaxf(1.0f / (1.0f + expf(-(s.z + bc))), 0.0f), 1.0f);
  o.w = fminf(fmaxf(1.0f / (1.0f + expf(-(s.w + bc))), 0.0f), 1.0f);
  *(float4*)&actt[idx * 4] = o;
}

// ---------------- votes: V[n][o][b][d] (f16) ----------------
__global__ __launch_bounds__(256) void k_votes(const float* __restrict__ poseT,
                                               const float* __restrict__ wcaps,
                                               unsigned* __restrict__ V) {
  __shared__ __align__(16) float wl[6400];
  __shared__ __align__(16) float pl[64 * 16];
  int n = blockIdx.x, t = threadIdx.x;
  const float* wsrc = wcaps + (size_t)n * 6400;
  for (int idx = t * 4; idx < 6400; idx += 1024)
    *(float4*)(wl + idx) = *(const float4*)(wsrc + idx);
  {
    float4 v = *(const float4*)(poseT + n * 1024 + t * 4);
    int i = (t * 4) >> 6, b = (t * 4) & 63;
    pl[(b+0)*16 + i] = v.x; pl[(b+1)*16 + i] = v.y;
    pl[(b+2)*16 + i] = v.z; pl[(b+3)*16 + i] = v.w;
  }
  __syncthreads();
  if (t >= 200) return;
  int o = t / 8, d0 = (t % 8) * 2;
  float w0[16], w1_[16];
#pragma unroll
  for (int i = 0; i < 16; ++i) {
    w0[i]  = wl[(i * 25 + o) * 16 + d0];
    w1_[i] = wl[(i * 25 + o) * 16 + d0 + 1];
  }
  unsigned* vd = V + (((size_t)n * 25 + o) * 64 * 16 + d0) / 2;
  for (int b = 0; b < 64; ++b) {
    const float* pb = &pl[b * 16];
    float a0 = 0.f, a1 = 0.f;
#pragma unroll
    for (int i = 0; i < 16; ++i) {
      float p = pb[i];
      a0 += p * w0[i];
      a1 += p * w1_[i];
    }
    vd[b * 8] = pack_f16(a0, a1);
  }
}

// ---------------- M-step moment accumulation (V f16, R f16) ----------------
template <bool UNIFORM>
__global__ __launch_bounds__(256) void k_stats(const unsigned* __restrict__ V,
                                               const float* __restrict__ actt,
                                               const unsigned short* __restrict__ Rh,
                                               float* __restrict__ part) {
  int o = blockIdx.y;
  int t = threadIdx.x, b = t & 63, wv = t >> 6;
  float S0 = 0.f, S1[16], S2[16];
#pragma unroll
  for (int d = 0; d < 16; ++d) { S1[d] = 0.f; S2[d] = 0.f; }
  int n0 = blockIdx.x * 64 + wv * 16;
#pragma unroll 2
  for (int k = 0; k < 16; ++k) {
    int n = n0 + k;
    float a = actt[n * 64 + b];
    float r = UNIFORM ? a * (1.0f / 25.0f)
                      : f16val(Rh[((size_t)n * 25 + o) * 64 + b]) * a;
    const uint4* vp = (const uint4*)(V + (((size_t)n * 25 + o) * 64 + b) * 8);
    uint4 u0 = vp[0], u1 = vp[1];
    unsigned uu[8] = {u0.x, u0.y, u0.z, u0.w, u1.x, u1.y, u1.z, u1.w};
    S0 += r;
#pragma unroll
    for (int q = 0; q < 8; ++q) {
      float v0 = f16lo(uu[q]), v1 = f16hi(uu[q]);
      float t0 = r * v0, t1 = r * v1;
      S1[2*q]   += t0;          S1[2*q+1] += t1;
      S2[2*q]   += t0 * v0;     S2[2*q+1] += t1 * v1;
    }
  }
  __shared__ float red[4 * 33 * 64];
  red[(wv * 33 + 0) * 64 + b] = S0;
#pragma unroll
  for (int d = 0; d < 16; ++d) {
    red[(wv * 33 + 1 + d) * 64 + b]  = S1[d];
    red[(wv * 33 + 17 + d) * 64 + b] = S2[d];
  }
  __syncthreads();
  if (wv == 0) {
    for (int s = 0; s < 33; ++s) {
      float tot = red[s * 64 + b] + red[(33 + s) * 64 + b] +
                  red[(66 + s) * 64 + b] + red[(99 + s) * 64 + b];
      part[((o * NCH + blockIdx.x) * 33 + s) * 64 + b] = tot;
    }
  }
}

// ---------------- merged reduce + finish (+ optional final outputs) ----------------
template <bool FINAL>
__global__ __launch_bounds__(256) void k_redfin(const float* __restrict__ part,
                                                const float* __restrict__ beta_u,
                                                const float* __restrict__ beta_a,
                                                float* __restrict__ mu,
                                                float* __restrict__ mi4,
                                                float* __restrict__ basew,
                                                const float* __restrict__ g2,
                                                const float* __restrict__ bb2,
                                                const float* __restrict__ w3,
                                                const float* __restrict__ b3,
                                                float* __restrict__ out) {
  __shared__ float st[33 * 64];
  int o = blockIdx.x, t = threadIdx.x;
  for (int slot = t; slot < 33 * 64; slot += 256) {
    float s = 0.f;
    const float* pp = part + (size_t)o * NCH * 2112 + slot;
    for (int c = 0; c < NCH; ++c) s += pp[(size_t)c * 2112];
    st[slot] = s;
  }
  __syncthreads();
  if (t < 64) {
    int b = t;
    float s0 = st[b];
    float rsm = s0 + EMEPS;
    float inv_rs = 1.0f / rsm;
    float ldet = 0.f;
    float mloc[16], iloc[16];
#pragma unroll
    for (int d = 0; d < 16; ++d) {
      float s1 = st[(1 + d) * 64 + b];
      float s2 = st[(17 + d) * 64 + b];
      float m = s1 * inv_rs;
      float var = (s2 - 2.0f * m * s1 + m * m * s0) * inv_rs;
      float sg = fmaxf(var, 0.0f) + EMEPS;
      mloc[d] = m;
      iloc[d] = 1.0f / sg;
      mu[(o * 16 + d) * 64 + b] = m;
      ldet += logf(sg);
    }
#pragma unroll
    for (int q = 0; q < 8; ++q) {
      float4 v = {mloc[2*q], iloc[2*q], mloc[2*q+1], iloc[2*q+1]};
      *(float4*)&mi4[((o * 8 + q) * 64 + b) * 4] = v;
    }
    float cost = (16.0f * beta_u[o] + 0.5f * ldet) * rsm;
    float x = beta_a[o] - cost;
    float a = 1.0f / (1.0f + expf(-x));
    basew[o * 64 + b] = logf(a + EMEPS) - 0.5f * ldet;

    if (FINAL) {
      float sm = 0.f;
#pragma unroll
      for (int d = 0; d < 16; ++d) sm += mloc[d];
      float mean = sm * (1.0f / 16.0f);
      float var2 = 0.f;
#pragma unroll
      for (int d = 0; d < 16; ++d) { float dd = mloc[d] - mean; var2 += dd * dd; }
      var2 *= (1.0f / 16.0f);
      float inv2 = 1.0f / sqrtf(var2 + LNEPS);
      float logit = 0.f, nrm = 0.f;
#pragma unroll
      for (int d = 0; d < 16; ++d) {
        float nh = (mloc[d] - mean) * inv2 * g2[d] + bb2[d];
        logit += nh * w3[d];
        nrm += mloc[d] * mloc[d];
      }
      out[b * 25 + o] = logit + b3[0];
      out[1600 + b * 25 + o] = sqrtf(nrm);
      float* pp = out + 3200 + (b * 25 + o) * 16;
#pragma unroll
      for (int d = 0; d < 16; ++d) pp[d] = mloc[d];
    }
  }
}

// ---------------- fused E-step: logp + softmax -> R (f16) or q ----------------
template <bool FINAL>
__global__ __launch_bounds__(256) void k_estep(const unsigned* __restrict__ V,
                                               const float* __restrict__ mi4,
                                               const float* __restrict__ basew,
                                               unsigned short* __restrict__ Rh,
                                               float* __restrict__ qout) {
  int t = threadIdx.x, b = t & 63, ng = t >> 6;
  int n = blockIdx.x * 4 + ng;
  float l[25];
  float mx = -1e30f;
#pragma unroll
  for (int o = 0; o < 25; ++o) {
    const uint4* vp = (const uint4*)(V + (((size_t)n * 25 + o) * 64 + b) * 8);
    uint4 u0 = vp[0], u1 = vp[1];
    unsigned uu[8] = {u0.x, u0.y, u0.z, u0.w, u1.x, u1.y, u1.z, u1.w};
    float acc = 0.f;
#pragma unroll
    for (int qq = 0; qq < 8; ++qq) {
      float4 mi = *(const float4*)&mi4[((o * 8 + qq) * 64 + b) * 4];
      float d0 = f16lo(uu[qq]) - mi.x;
      float d1 = f16hi(uu[qq]) - mi.z;
      acc += d0 * d0 * mi.y + d1 * d1 * mi.w;
    }
    l[o] = basew[o * 64 + b] - 0.5f * acc;
    mx = fmaxf(mx, l[o]);
  }
  float s = 0.f;
#pragma unroll
  for (int o = 0; o < 25; ++o) { l[o] = expf(l[o] - mx); s += l[o]; }
  float inv = 1.0f / s;
  if (FINAL) {
    float* qp = qout + ((size_t)b * NPRI + n) * 25;
#pragma unroll
    for (int o = 0; o < 25; ++o) qp[o] = l[o] * inv;
  } else {
#pragma unroll
    for (int o = 0; o < 25; ++o)
      Rh[((size_t)n * 25 + o) * 64 + b] = f16bits(l[o] * inv);
  }
}

extern "C" void kernel_launch(void* const* d_in, const int* in_sizes, int n_in,
                              void* d_out, int out_size, void* d_ws, size_t ws_size,
                              hipStream_t stream) {
  const float* z      = (const float*)d_in[0];
  const float* w1     = (const float*)d_in[1];
  const float* b1     = (const float*)d_in[2];
  const float* ln1g   = (const float*)d_in[3];
  const float* ln1b   = (const float*)d_in[4];
  const float* w2     = (const float*)d_in[5];
  const float* b2     = (const float*)d_in[6];
  const float* wcaps  = (const float*)d_in[7];
  const float* beta_u = (const float*)d_in[8];
  const float* beta_a = (const float*)d_in[9];
  const float* ln2g   = (const float*)d_in[10];
  const float* ln2b   = (const float*)d_in[11];
  const float* w3     = (const float*)d_in[12];
  const float* b3     = (const float*)d_in[13];

  if (ws_size < (size_t)WS_FLOATS * 4) {
    fprintf(stderr, "kernel_launch: ws too small: %zu < %zu bytes\n",
            ws_size, (size_t)WS_FLOATS * 4);
  }

  float* ws    = (float*)d_ws;
  float* out   = (float*)d_out;
  float* poseT = ws + OFF_POSE;
  float* zn    = ws + OFF_ZN;
  float* actt  = ws + OFF_ACTT;
  float* g2p   = ws + OFF_G2P;
  unsigned* V  = (unsigned*)(ws + OFF_V);
  unsigned short* Rh = (unsigned short*)(ws + OFF_R);
  float* part  = ws + OFF_PART;
  float* muw   = ws + OFF_MU;
  float* mi4   = ws + OFF_MI4;
  float* bse   = ws + OFF_BASE;
  unsigned* zh = (unsigned*)(ws + OFF_ZH);

  k_lnzh<<<64, 256, 0, stream>>>(z, ln1g, ln1b, zn, zh);
  k_gemm1m<<<512, 512, 0, stream>>>(zh, w1, b1, poseT);
  k_gemm2p<<<dim3(32, KS2), 256, 0, stream>>>(zn, w2, g2p);
  k_gemm2r<<<128, 256, 0, stream>>>(g2p, b2, actt);
  k_votes<<<2048, 256, 0, stream>>>(poseT, wcaps, V);

  // iteration 1 (uniform R)
  k_stats<true><<<dim3(NCH, 25), 256, 0, stream>>>(V, actt, Rh, part);
  k_redfin<false><<<25, 256, 0, stream>>>(part, beta_u, beta_a, muw, mi4, bse,
                                          ln2g, ln2b, w3, b3, out);

  // iteration 2
  k_estep<false><<<512, 256, 0, stream>>>(V, mi4, bse, Rh, nullptr);
  k_stats<false><<<dim3(NCH, 25), 256, 0, stream>>>(V, actt, Rh, part);
  k_redfin<false><<<25, 256, 0, stream>>>(part, beta_u, beta_a, muw, mi4, bse,
                                          ln2g, ln2b, w3, b3, out);

  // iteration 3 (final M-step also writes logits/acts/pose)
  k_estep<false><<<512, 256, 0, stream>>>(V, mi4, bse, Rh, nullptr);
  k_stats<false><<<dim3(NCH, 25), 256, 0, stream>>>(V, actt, Rh, part);
  k_redfin<true><<<25, 256, 0, stream>>>(part, beta_u, beta_a, muw, mi4, bse,
                                         ln2g, ln2b, w3, b3, out);

  // final E-step -> q
  k_estep<true><<<512, 256, 0, stream>>>(V, mi4, bse, nullptr, out + 28800);
}

// Round 9
// 350.028 us; speedup vs baseline: 1.7561x; 1.0891x over previous
//
#include <hip/hip_runtime.h>
#include <hip/hip_bf16.h>
#include <cstdio>

#define B     64
#define DIN   1024
#define NPRI  2048
#define DPRI  16
#define NCLS  25
#define DCLS  16
#define EMEPS 1e-6f
#define LNEPS 1e-5f
#define KS2   8
#define NCH   16

// ---------------- workspace layout (float offsets) ----------------
#define OFF_POSE 0                                   // poseT [NPRI*DPRI][B] f32
#define OFF_ZN   (OFF_POSE + NPRI*DPRI*B)            // [B][DIN]
#define OFF_ACTT (OFF_ZN + B*DIN)                    // [NPRI][B]
#define OFF_G2P  (OFF_ACTT + NPRI*B)                 // gemm2 partial [KS2][NPRI][B]
#define OFF_V    (OFF_G2P + KS2*NPRI*B)              // f16 [NPRI][NCLS][B][DCLS]
#define V_FLOATS (NPRI*NCLS*B*DCLS/2)
#define OFF_R    (OFF_V + V_FLOATS)                  // f16 [NPRI][NCLS][B]
#define R_FLOATS (NPRI*NCLS*B/2)
#define OFF_PART (OFF_R + R_FLOATS)                  // [NCLS][NCH][33][B]
#define OFF_MU   (OFF_PART + NCLS*NCH*33*B)          // [NCLS][DCLS][B]
#define OFF_MI4  (OFF_MU + NCLS*DCLS*B)              // float4 [NCLS][8][B]
#define OFF_BASE (OFF_MI4 + NCLS*8*B*4)              // [NCLS][B]
#define OFF_ZH   (OFF_BASE + NCLS*B)                 // fp16 z [B][DIN]
#define WS_FLOATS (OFF_ZH + B*DIN/2)

typedef __attribute__((ext_vector_type(8))) _Float16 f16x8;
typedef __attribute__((ext_vector_type(4))) float f32x4;

__device__ __forceinline__ unsigned pack_f16(float a, float b) {
  union { _Float16 h[2]; unsigned u; } x;
  x.h[0] = (_Float16)a; x.h[1] = (_Float16)b;
  return x.u;
}
__device__ __forceinline__ float f16lo(unsigned u) {
  union { unsigned u; _Float16 h[2]; } x; x.u = u; return (float)x.h[0];
}
__device__ __forceinline__ float f16hi(unsigned u) {
  union { unsigned u; _Float16 h[2]; } x; x.u = u; return (float)x.h[1];
}
__device__ __forceinline__ unsigned short f16bits(float a) {
  union { _Float16 h; unsigned short u; } x; x.h = (_Float16)a; return x.u;
}
__device__ __forceinline__ float f16val(unsigned short u) {
  union { unsigned short u; _Float16 h; } x; x.u = u; return (float)x.h;
}

// ---------------- LayerNorm + z->fp16 ----------------
__global__ __launch_bounds__(256) void k_lnzh(const float* __restrict__ z,
                                              const float* __restrict__ g,
                                              const float* __restrict__ bb,
                                              float* __restrict__ zn,
                                              unsigned* __restrict__ zh) {
  int row = blockIdx.x, t = threadIdx.x;
  const float* zr = z + row * DIN;
  float4 v = ((const float4*)zr)[t];
  uint2 hz = {pack_f16(v.x, v.y), pack_f16(v.z, v.w)};
  *(uint2*)&zh[row * 512 + t * 2] = hz;
  float s  = v.x + v.y + v.z + v.w;
  float s2 = v.x*v.x + v.y*v.y + v.z*v.z + v.w*v.w;
  for (int off = 32; off; off >>= 1) {
    s  += __shfl_down(s, off);
    s2 += __shfl_down(s2, off);
  }
  __shared__ float ls[8];
  int wv = t >> 6, ln = t & 63;
  if (ln == 0) { ls[wv*2] = s; ls[wv*2+1] = s2; }
  __syncthreads();
  s  = ls[0] + ls[2] + ls[4] + ls[6];
  s2 = ls[1] + ls[3] + ls[5] + ls[7];
  float mean = s * (1.0f / DIN);
  float var  = s2 * (1.0f / DIN) - mean * mean;
  float inv  = 1.0f / sqrtf(var + LNEPS);
  float4 gg = ((const float4*)g)[t];
  float4 bv = ((const float4*)bb)[t];
  float4 o;
  o.x = (v.x - mean) * inv * gg.x + bv.x;
  o.y = (v.y - mean) * inv * gg.y + bv.y;
  o.z = (v.z - mean) * inv * gg.z + bv.z;
  o.w = (v.w - mean) * inv * gg.w + bv.w;
  ((float4*)(zn + row * DIN))[t] = o;
}

// ---------------- GEMM1 via fp16 MFMA, 8 waves, in-block k-split (round-6 proven) ----------------
__global__ __launch_bounds__(512) void k_gemm1m(const unsigned* __restrict__ zh,
                                                const float* __restrict__ w1,
                                                const float* __restrict__ b1,
                                                float* __restrict__ poseT) {
  __shared__ __align__(16) unsigned bt[2][64 * 68];
  __shared__ __align__(16) unsigned zl[2][64 * 68];
  int t = threadIdx.x;
  int c0 = blockIdx.x * 64;
  int l = t & 63, w = t >> 6;
  int kh = w >> 2, cw = w & 3;
  int c15 = l & 15, kq = l >> 4;
  int h  = t >> 8;
  int th = t & 255;
  int s_kp = th >> 2;
  int s_q  = th & 3;

  f32x4 acc0 = {0,0,0,0}, acc1 = {0,0,0,0}, acc2 = {0,0,0,0}, acc3 = {0,0,0,0};

  for (int it = 0; it < 4; ++it) {
    int k0 = (h * 4 + it) * 128;
#pragma unroll
    for (int u = 0; u < 4; ++u) {
      int cq = s_q + 4 * u;
      const float* src0 = w1 + (size_t)(k0 + 2 * s_kp) * 32768 + c0 + cq * 4;
      float4 r0 = *(const float4*)src0;
      float4 r1 = *(const float4*)(src0 + 32768);
      unsigned* dst = &bt[h][(cq * 4) * 68 + s_kp];
      dst[0]   = pack_f16(r0.x, r1.x);
      dst[68]  = pack_f16(r0.y, r1.y);
      dst[136] = pack_f16(r0.z, r1.z);
      dst[204] = pack_f16(r0.w, r1.w);
    }
#pragma unroll
    for (int u = 0; u < 4; ++u) {
      int ku4 = s_q + 4 * u;
      uint4 v = *(const uint4*)&zh[(size_t)s_kp * 512 + (k0 >> 1) + ku4 * 4];
      *(uint4*)&zl[h][s_kp * 68 + ku4 * 4] = v;
    }
    __syncthreads();
#pragma unroll
    for (int ks = 0; ks < 4; ++ks) {
      union { uint4 u; f16x8 hh; } bf, a0, a1, a2, a3;
      bf.u = *(const uint4*)&bt[kh][(cw * 16 + c15) * 68 + ks * 16 + kq * 4];
      a0.u = *(const uint4*)&zl[kh][(c15)      * 68 + ks * 16 + kq * 4];
      a1.u = *(const uint4*)&zl[kh][(16 + c15) * 68 + ks * 16 + kq * 4];
      a2.u = *(const uint4*)&zl[kh][(32 + c15) * 68 + ks * 16 + kq * 4];
      a3.u = *(const uint4*)&zl[kh][(48 + c15) * 68 + ks * 16 + kq * 4];
      acc0 = __builtin_amdgcn_mfma_f32_16x16x32_f16(a0.hh, bf.hh, acc0, 0, 0, 0);
      acc1 = __builtin_amdgcn_mfma_f32_16x16x32_f16(a1.hh, bf.hh, acc1, 0, 0, 0);
      acc2 = __builtin_amdgcn_mfma_f32_16x16x32_f16(a2.hh, bf.hh, acc2, 0, 0, 0);
      acc3 = __builtin_amdgcn_mfma_f32_16x16x32_f16(a3.hh, bf.hh, acc3, 0, 0, 0);
    }
    __syncthreads();
  }

  float* red = (float*)&zl[0][0];
  if (kh == 1) {
    int cc = cw * 16 + c15;
    *(float4*)&red[cc * 68 + kq * 4]      = *(float4*)&acc0;
    *(float4*)&red[cc * 68 + 16 + kq * 4] = *(float4*)&acc1;
    *(float4*)&red[cc * 68 + 32 + kq * 4] = *(float4*)&acc2;
    *(float4*)&red[cc * 68 + 48 + kq * 4] = *(float4*)&acc3;
  }
  __syncthreads();
  if (kh == 0) {
    int cc = cw * 16 + c15;
    int c = c0 + cc;
    float bc = b1[c];
    float4 r0 = *(float4*)&red[cc * 68 + kq * 4];
    float4 r1 = *(float4*)&red[cc * 68 + 16 + kq * 4];
    float4 r2 = *(float4*)&red[cc * 68 + 32 + kq * 4];
    float4 r3 = *(float4*)&red[cc * 68 + 48 + kq * 4];
    float* pdst = poseT + (size_t)c * 64 + kq * 4;
    float4 o0 = {acc0[0] + r0.x + bc, acc0[1] + r0.y + bc, acc0[2] + r0.z + bc, acc0[3] + r0.w + bc};
    float4 o1 = {acc1[0] + r1.x + bc, acc1[1] + r1.y + bc, acc1[2] + r1.z + bc, acc1[3] + r1.w + bc};
    float4 o2 = {acc2[0] + r2.x + bc, acc2[1] + r2.y + bc, acc2[2] + r2.z + bc, acc2[3] + r2.w + bc};
    float4 o3 = {acc3[0] + r3.x + bc, acc3[1] + r3.y + bc, acc3[2] + r3.z + bc, acc3[3] + r3.w + bc};
    *(float4*)&pdst[0]  = o0;
    *(float4*)&pdst[16] = o1;
    *(float4*)&pdst[32] = o2;
    *(float4*)&pdst[48] = o3;
  }
}

// ---------------- GEMM2 k-split partial ----------------
__global__ __launch_bounds__(256, 2) void k_gemm2p(const float* __restrict__ zn,
                                                   const float* __restrict__ w2,
                                                   float* __restrict__ part) {
  __shared__ __align__(16) float znT[128 * 68];
  __shared__ __align__(16) float wl[128 * 68];
  int t = threadIdx.x;
  int c0 = blockIdx.x * 64;
  int k0 = blockIdx.y * 128;
  int zr_ = t >> 2, za = t & 3;
  int wk = t >> 1, wc = (t & 1) * 32;

#pragma unroll
  for (int jj = 0; jj < 4; ++jj) {
    int kb = za * 8 + jj * 32;
    const float* src = zn + zr_ * DIN + k0 + kb;
    float4 v0 = *(const float4*)src;
    float4 v1 = *(const float4*)(src + 4);
    znT[(kb+0)*68 + zr_] = v0.x; znT[(kb+1)*68 + zr_] = v0.y;
    znT[(kb+2)*68 + zr_] = v0.z; znT[(kb+3)*68 + zr_] = v0.w;
    znT[(kb+4)*68 + zr_] = v1.x; znT[(kb+5)*68 + zr_] = v1.y;
    znT[(kb+6)*68 + zr_] = v1.z; znT[(kb+7)*68 + zr_] = v1.w;
  }
  const float* wsrc = w2 + (size_t)(k0 + wk) * NPRI + c0 + wc;
#pragma unroll
  for (int j = 0; j < 8; ++j)
    *(float4*)&wl[wk * 68 + wc + j * 4] = *(const float4*)(wsrc + j * 4);
  __syncthreads();

  int r0 = (t >> 4) * 4, c0l = (t & 15) * 4;
  float acc[4][4];
#pragma unroll
  for (int j = 0; j < 4; ++j)
#pragma unroll
    for (int i = 0; i < 4; ++i) acc[j][i] = 0.f;

#pragma unroll 4
  for (int k = 0; k < 128; ++k) {
    float4 z4 = *(const float4*)&znT[k * 68 + r0];
    float4 w4 = *(const float4*)&wl[k * 68 + c0l];
    float zz[4] = {z4.x, z4.y, z4.z, z4.w};
    float ww[4] = {w4.x, w4.y, w4.z, w4.w};
#pragma unroll
    for (int j = 0; j < 4; ++j)
#pragma unroll
      for (int i = 0; i < 4; ++i) acc[j][i] += ww[j] * zz[i];
  }
  float* pdst = part + ((size_t)blockIdx.y * NPRI + c0 + c0l) * 64 + r0;
#pragma unroll
  for (int j = 0; j < 4; ++j) {
    float4 o = {acc[j][0], acc[j][1], acc[j][2], acc[j][3]};
    *(float4*)&pdst[j * 64] = o;
  }
}

__global__ __launch_bounds__(256) void k_gemm2r(const float* __restrict__ part,
                                                const float* __restrict__ b2,
                                                float* __restrict__ actt) {
  int idx = blockIdx.x * 256 + threadIdx.x;
  float4 s = {0.f, 0.f, 0.f, 0.f};
#pragma unroll
  for (int kz = 0; kz < KS2; ++kz) {
    float4 v = *(const float4*)&part[(size_t)kz * NPRI * 64 + idx * 4];
    s.x += v.x; s.y += v.y; s.z += v.z; s.w += v.w;
  }
  int c = (idx * 4) >> 6;
  float bc = b2[c];
  float4 o;
  o.x = fminf(fmaxf(1.0f / (1.0f + expf(-(s.x + bc))), 0.0f), 1.0f);
  o.y = fminf(fmaxf(1.0f / (1.0f + expf(-(s.y + bc))), 0.0f), 1.0f);
  o.z = fminf(fmaxf(1.0f / (1.0f + expf(-(s.z + bc))), 0.0f), 1.0f);
  o.w = fminf(fmaxf(1.0f / (1.0f + expf(-(s.w + bc))), 0.0f), 1.0f);
  *(float4*)&actt[idx * 4] = o;
}

// ---------------- votes: V[n][o][b][d] (f16) ----------------
__global__ __launch_bounds__(256) void k_votes(const float* __restrict__ poseT,
                                               const float* __restrict__ wcaps,
                                               unsigned* __restrict__ V) {
  __shared__ __align__(16) float wl[6400];
  __shared__ __align__(16) float pl[64 * 16];
  int n = blockIdx.x, t = threadIdx.x;
  const float* wsrc = wcaps + (size_t)n * 6400;
  for (int idx = t * 4; idx < 6400; idx += 1024)
    *(float4*)(wl + idx) = *(const float4*)(wsrc + idx);
  {
    float4 v = *(const float4*)(poseT + n * 1024 + t * 4);
    int i = (t * 4) >> 6, b = (t * 4) & 63;
    pl[(b+0)*16 + i] = v.x; pl[(b+1)*16 + i] = v.y;
    pl[(b+2)*16 + i] = v.z; pl[(b+3)*16 + i] = v.w;
  }
  __syncthreads();
  if (t >= 200) return;
  int o = t / 8, d0 = (t % 8) * 2;
  float w0[16], w1_[16];
#pragma unroll
  for (int i = 0; i < 16; ++i) {
    w0[i]  = wl[(i * 25 + o) * 16 + d0];
    w1_[i] = wl[(i * 25 + o) * 16 + d0 + 1];
  }
  unsigned* vd = V + (((size_t)n * 25 + o) * 64 * 16 + d0) / 2;
  for (int b = 0; b < 64; ++b) {
    const float* pb = &pl[b * 16];
    float a0 = 0.f, a1 = 0.f;
#pragma unroll
    for (int i = 0; i < 16; ++i) {
      float p = pb[i];
      a0 += p * w0[i];
      a1 += p * w1_[i];
    }
    vd[b * 8] = pack_f16(a0, a1);
  }
}

// ---------------- M-step moment accumulation (V f16, R f16) — round-6 chunking ----------------
template <bool UNIFORM>
__global__ __launch_bounds__(256) void k_stats(const unsigned* __restrict__ V,
                                               const float* __restrict__ actt,
                                               const unsigned short* __restrict__ Rh,
                                               float* __restrict__ part) {
  int o = blockIdx.y;
  int t = threadIdx.x, b = t & 63, wv = t >> 6;
  float S0 = 0.f, S1[16], S2[16];
#pragma unroll
  for (int d = 0; d < 16; ++d) { S1[d] = 0.f; S2[d] = 0.f; }
  int n0 = blockIdx.x * 128 + wv * 32;
  for (int k = 0; k < 32; ++k) {
    int n = n0 + k;
    float a = actt[n * 64 + b];
    float r = UNIFORM ? a * (1.0f / 25.0f)
                      : f16val(Rh[((size_t)n * 25 + o) * 64 + b]) * a;
    const uint4* vp = (const uint4*)(V + (((size_t)n * 25 + o) * 64 + b) * 8);
    uint4 u0 = vp[0], u1 = vp[1];
    unsigned uu[8] = {u0.x, u0.y, u0.z, u0.w, u1.x, u1.y, u1.z, u1.w};
    S0 += r;
#pragma unroll
    for (int q = 0; q < 8; ++q) {
      float v0 = f16lo(uu[q]), v1 = f16hi(uu[q]);
      float t0 = r * v0, t1 = r * v1;
      S1[2*q]   += t0;          S1[2*q+1] += t1;
      S2[2*q]   += t0 * v0;     S2[2*q+1] += t1 * v1;
    }
  }
  __shared__ float red[4 * 33 * 64];
  red[(wv * 33 + 0) * 64 + b] = S0;
#pragma unroll
  for (int d = 0; d < 16; ++d) {
    red[(wv * 33 + 1 + d) * 64 + b]  = S1[d];
    red[(wv * 33 + 17 + d) * 64 + b] = S2[d];
  }
  __syncthreads();
  if (wv == 0) {
    for (int s = 0; s < 33; ++s) {
      float tot = red[s * 64 + b] + red[(33 + s) * 64 + b] +
                  red[(66 + s) * 64 + b] + red[(99 + s) * 64 + b];
      part[((o * NCH + blockIdx.x) * 33 + s) * 64 + b] = tot;
    }
  }
}

// ---------------- merged reduce + finish (+ optional final outputs) ----------------
template <bool FINAL>
__global__ __launch_bounds__(256) void k_redfin(const float* __restrict__ part,
                                                const float* __restrict__ beta_u,
                                                const float* __restrict__ beta_a,
                                                float* __restrict__ mi4,
                                                float* __restrict__ basew,
                                                const float* __restrict__ g2,
                                                const float* __restrict__ bb2,
                                                const float* __restrict__ w3,
                                                const float* __restrict__ b3,
                                                float* __restrict__ out) {
  __shared__ float st[33 * 64];
  int o = blockIdx.x, t = threadIdx.x;
  for (int slot = t; slot < 33 * 64; slot += 256) {
    float s = 0.f;
    const float* pp = part + (size_t)o * NCH * 2112 + slot;
#pragma unroll
    for (int c = 0; c < NCH; ++c) s += pp[(size_t)c * 2112];
    st[slot] = s;
  }
  __syncthreads();
  if (t < 64) {
    int b = t;
    float s0 = st[b];
    float rsm = s0 + EMEPS;
    float inv_rs = 1.0f / rsm;
    float ldet = 0.f;
    float mloc[16], iloc[16];
#pragma unroll
    for (int d = 0; d < 16; ++d) {
      float s1 = st[(1 + d) * 64 + b];
      float s2 = st[(17 + d) * 64 + b];
      float m = s1 * inv_rs;
      float var = (s2 - 2.0f * m * s1 + m * m * s0) * inv_rs;
      float sg = fmaxf(var, 0.0f) + EMEPS;
      mloc[d] = m;
      iloc[d] = 1.0f / sg;
      ldet += logf(sg);
    }
#pragma unroll
    for (int q = 0; q < 8; ++q) {
      float4 v = {mloc[2*q], iloc[2*q], mloc[2*q+1], iloc[2*q+1]};
      *(float4*)&mi4[((o * 8 + q) * 64 + b) * 4] = v;
    }
    float cost = (16.0f * beta_u[o] + 0.5f * ldet) * rsm;
    float x = beta_a[o] - cost;
    float a = 1.0f / (1.0f + expf(-x));
    basew[o * 64 + b] = logf(a + EMEPS) - 0.5f * ldet;

    if (FINAL) {
      float sm = 0.f;
#pragma unroll
      for (int d = 0; d < 16; ++d) sm += mloc[d];
      float mean = sm * (1.0f / 16.0f);
      float var2 = 0.f;
#pragma unroll
      for (int d = 0; d < 16; ++d) { float dd = mloc[d] - mean; var2 += dd * dd; }
      var2 *= (1.0f / 16.0f);
      float inv2 = 1.0f / sqrtf(var2 + LNEPS);
      float logit = 0.f, nrm = 0.f;
#pragma unroll
      for (int d = 0; d < 16; ++d) {
        float nh = (mloc[d] - mean) * inv2 * g2[d] + bb2[d];
        logit += nh * w3[d];
        nrm += mloc[d] * mloc[d];
      }
      out[b * 25 + o] = logit + b3[0];
      out[1600 + b * 25 + o] = sqrtf(nrm);
      float* pp = out + 3200 + (b * 25 + o) * 16;
#pragma unroll
      for (int d = 0; d < 16; ++d) pp[d] = mloc[d];
    }
  }
}

// ---------------- fused E-step: logp + softmax -> R (f16) or q ----------------
template <bool FINAL>
__global__ __launch_bounds__(256) void k_estep(const unsigned* __restrict__ V,
                                               const float* __restrict__ mi4,
                                               const float* __restrict__ basew,
                                               unsigned short* __restrict__ Rh,
                                               float* __restrict__ qout) {
  int t = threadIdx.x, b = t & 63, ng = t >> 6;
  int n = blockIdx.x * 4 + ng;
  float l[25];
  float mx = -1e30f;
#pragma unroll
  for (int o = 0; o < 25; ++o) {
    const uint4* vp = (const uint4*)(V + (((size_t)n * 25 + o) * 64 + b) * 8);
    uint4 u0 = vp[0], u1 = vp[1];
    unsigned uu[8] = {u0.x, u0.y, u0.z, u0.w, u1.x, u1.y, u1.z, u1.w};
    float acc = 0.f;
#pragma unroll
    for (int qq = 0; qq < 8; ++qq) {
      float4 mi = *(const float4*)&mi4[((o * 8 + qq) * 64 + b) * 4];
      float d0 = f16lo(uu[qq]) - mi.x;
      float d1 = f16hi(uu[qq]) - mi.z;
      acc += d0 * d0 * mi.y + d1 * d1 * mi.w;
    }
    l[o] = basew[o * 64 + b] - 0.5f * acc;
    mx = fmaxf(mx, l[o]);
  }
  float s = 0.f;
#pragma unroll
  for (int o = 0; o < 25; ++o) { l[o] = expf(l[o] - mx); s += l[o]; }
  float inv = 1.0f / s;
  if (FINAL) {
    float* qp = qout + ((size_t)b * NPRI + n) * 25;
#pragma unroll
    for (int o = 0; o < 25; ++o) qp[o] = l[o] * inv;
  } else {
#pragma unroll
    for (int o = 0; o < 25; ++o)
      Rh[((size_t)n * 25 + o) * 64 + b] = f16bits(l[o] * inv);
  }
}

extern "C" void kernel_launch(void* const* d_in, const int* in_sizes, int n_in,
                              void* d_out, int out_size, void* d_ws, size_t ws_size,
                              hipStream_t stream) {
  const float* z      = (const float*)d_in[0];
  const float* w1     = (const float*)d_in[1];
  const float* b1     = (const float*)d_in[2];
  const float* ln1g   = (const float*)d_in[3];
  const float* ln1b   = (const float*)d_in[4];
  const float* w2     = (const float*)d_in[5];
  const float* b2     = (const float*)d_in[6];
  const float* wcaps  = (const float*)d_in[7];
  const float* beta_u = (const float*)d_in[8];
  const float* beta_a = (const float*)d_in[9];
  const float* ln2g   = (const float*)d_in[10];
  const float* ln2b   = (const float*)d_in[11];
  const float* w3     = (const float*)d_in[12];
  const float* b3     = (const float*)d_in[13];

  if (ws_size < (size_t)WS_FLOATS * 4) {
    fprintf(stderr, "kernel_launch: ws too small: %zu < %zu bytes\n",
            ws_size, (size_t)WS_FLOATS * 4);
  }

  float* ws    = (float*)d_ws;
  float* out   = (float*)d_out;
  float* poseT = ws + OFF_POSE;
  float* zn    = ws + OFF_ZN;
  float* actt  = ws + OFF_ACTT;
  float* g2p   = ws + OFF_G2P;
  unsigned* V  = (unsigned*)(ws + OFF_V);
  unsigned short* Rh = (unsigned short*)(ws + OFF_R);
  float* part  = ws + OFF_PART;
  float* mi4   = ws + OFF_MI4;
  float* bse   = ws + OFF_BASE;
  unsigned* zh = (unsigned*)(ws + OFF_ZH);

  k_lnzh<<<64, 256, 0, stream>>>(z, ln1g, ln1b, zn, zh);
  k_gemm1m<<<512, 512, 0, stream>>>(zh, w1, b1, poseT);
  k_gemm2p<<<dim3(32, KS2), 256, 0, stream>>>(zn, w2, g2p);
  k_gemm2r<<<128, 256, 0, stream>>>(g2p, b2, actt);
  k_votes<<<2048, 256, 0, stream>>>(poseT, wcaps, V);

  // iteration 1 (uniform R)
  k_stats<true><<<dim3(NCH, 25), 256, 0, stream>>>(V, actt, Rh, part);
  k_redfin<false><<<25, 256, 0, stream>>>(part, beta_u, beta_a, mi4, bse,
                                          ln2g, ln2b, w3, b3, out);

  // iteration 2
  k_estep<false><<<512, 256, 0, stream>>>(V, mi4, bse, Rh, nullptr);
  k_stats<false><<<dim3(NCH, 25), 256, 0, stream>>>(V, actt, Rh, part);
  k_redfin<false><<<25, 256, 0, stream>>>(part, beta_u, beta_a, mi4, bse,
                                          ln2g, ln2b, w3, b3, out);

  // iteration 3 (final M-step also writes logits/acts/pose)
  k_estep<false><<<512, 256, 0, stream>>>(V, mi4, bse, Rh, nullptr);
  k_stats<false><<<dim3(NCH, 25), 256, 0, stream>>>(V, actt, Rh, part);
  k_redfin<true><<<25, 256, 0, stream>>>(part, beta_u, beta_a, mi4, bse,
                                         ln2g, ln2b, w3, b3, out);

  // final E-step -> q
  k_estep<true><<<512, 256, 0, stream>>>(V, mi4, bse, nullptr, out + 28800);
}

// Round 10
// 349.966 us; speedup vs baseline: 1.7564x; 1.0002x over previous
//
#include <hip/hip_runtime.h>
#include <hip/hip_bf16.h>
#include <cstdio>

#define B     64
#define DIN   1024
#define NPRI  2048
#define DPRI  16
#define NCLS  25
#define DCLS  16
#define EMEPS 1e-6f
#define LNEPS 1e-5f
#define KS2   8
#define NCH   16

// ---------------- workspace layout (float offsets) ----------------
#define OFF_POSE 0                                   // posePart [2][NPRI*DPRI][B] f32 (k-halves)
#define OFF_ZN   (OFF_POSE + 2*NPRI*DPRI*B)          // [B][DIN]
#define OFF_ACTT (OFF_ZN + B*DIN)                    // [NPRI][B]
#define OFF_G2P  (OFF_ACTT + NPRI*B)                 // gemm2 partial [KS2][NPRI][B]
#define OFF_V    (OFF_G2P + KS2*NPRI*B)              // f16 [NPRI][NCLS][B][DCLS]
#define V_FLOATS (NPRI*NCLS*B*DCLS/2)
#define OFF_R    (OFF_V + V_FLOATS)                  // f16 [NPRI][NCLS][B]
#define R_FLOATS (NPRI*NCLS*B/2)
#define OFF_PART (OFF_R + R_FLOATS)                  // [NCLS][NCH][33][B]
#define OFF_MI4  (OFF_PART + NCLS*NCH*33*B)          // float4 [NCLS][8][B]
#define OFF_BASE (OFF_MI4 + NCLS*8*B*4)              // [NCLS][B]
#define OFF_ZH   (OFF_BASE + NCLS*B)                 // fp16 z [B][DIN]
#define WS_FLOATS (OFF_ZH + B*DIN/2)

typedef __attribute__((ext_vector_type(8))) _Float16 f16x8;
typedef __attribute__((ext_vector_type(4))) float f32x4;

__device__ __forceinline__ unsigned pack_f16(float a, float b) {
  union { _Float16 h[2]; unsigned u; } x;
  x.h[0] = (_Float16)a; x.h[1] = (_Float16)b;
  return x.u;
}
__device__ __forceinline__ float f16lo(unsigned u) {
  union { unsigned u; _Float16 h[2]; } x; x.u = u; return (float)x.h[0];
}
__device__ __forceinline__ float f16hi(unsigned u) {
  union { unsigned u; _Float16 h[2]; } x; x.u = u; return (float)x.h[1];
}
__device__ __forceinline__ unsigned short f16bits(float a) {
  union { _Float16 h; unsigned short u; } x; x.h = (_Float16)a; return x.u;
}
__device__ __forceinline__ float f16val(unsigned short u) {
  union { unsigned short u; _Float16 h; } x; x.u = u; return (float)x.h;
}

// ---------------- LayerNorm + z->fp16 ----------------
__global__ __launch_bounds__(256) void k_lnzh(const float* __restrict__ z,
                                              const float* __restrict__ g,
                                              const float* __restrict__ bb,
                                              float* __restrict__ zn,
                                              unsigned* __restrict__ zh) {
  int row = blockIdx.x, t = threadIdx.x;
  const float* zr = z + row * DIN;
  float4 v = ((const float4*)zr)[t];
  uint2 hz = {pack_f16(v.x, v.y), pack_f16(v.z, v.w)};
  *(uint2*)&zh[row * 512 + t * 2] = hz;
  float s  = v.x + v.y + v.z + v.w;
  float s2 = v.x*v.x + v.y*v.y + v.z*v.z + v.w*v.w;
  for (int off = 32; off; off >>= 1) {
    s  += __shfl_down(s, off);
    s2 += __shfl_down(s2, off);
  }
  __shared__ float ls[8];
  int wv = t >> 6, ln = t & 63;
  if (ln == 0) { ls[wv*2] = s; ls[wv*2+1] = s2; }
  __syncthreads();
  s  = ls[0] + ls[2] + ls[4] + ls[6];
  s2 = ls[1] + ls[3] + ls[5] + ls[7];
  float mean = s * (1.0f / DIN);
  float var  = s2 * (1.0f / DIN) - mean * mean;
  float inv  = 1.0f / sqrtf(var + LNEPS);
  float4 gg = ((const float4*)g)[t];
  float4 bv = ((const float4*)bb)[t];
  float4 o;
  o.x = (v.x - mean) * inv * gg.x + bv.x;
  o.y = (v.y - mean) * inv * gg.y + bv.y;
  o.z = (v.z - mean) * inv * gg.z + bv.z;
  o.w = (v.w - mean) * inv * gg.w + bv.w;
  ((float4*)(zn + row * DIN))[t] = o;
}

// ---------------- GEMM1 via fp16 MFMA: grid (512 col-tiles, 2 k-halves), 4 waves ----------------
// Each block: 64 cols, one K-half (512 k) in 4 chunks of 128. LDS 34.8 KB -> 4 blocks/CU.
// Writes f32 partial posePart[kh][c][r] (no bias); votes sums halves + bias.
__global__ __launch_bounds__(256) void k_gemm1m(const unsigned* __restrict__ zh,
                                                const float* __restrict__ w1,
                                                float* __restrict__ poseP) {
  __shared__ __align__(16) unsigned bt[64 * 68];
  __shared__ __align__(16) unsigned zl[64 * 68];
  int t = threadIdx.x;
  int c0 = blockIdx.x * 64;
  int kh = blockIdx.y;
  int l = t & 63, cw = t >> 6;
  int c15 = l & 15, kq = l >> 4;
  int s_kp = t >> 2;
  int s_q  = t & 3;

  f32x4 acc0 = {0,0,0,0}, acc1 = {0,0,0,0}, acc2 = {0,0,0,0}, acc3 = {0,0,0,0};

  for (int it = 0; it < 4; ++it) {
    int k0 = (kh * 4 + it) * 128;
    if (it) __syncthreads();
#pragma unroll
    for (int u = 0; u < 4; ++u) {
      int cq = s_q + 4 * u;
      const float* src0 = w1 + (size_t)(k0 + 2 * s_kp) * 32768 + c0 + cq * 4;
      float4 r0 = *(const float4*)src0;
      float4 r1 = *(const float4*)(src0 + 32768);
      unsigned* dst = &bt[(cq * 4) * 68 + s_kp];
      dst[0]   = pack_f16(r0.x, r1.x);
      dst[68]  = pack_f16(r0.y, r1.y);
      dst[136] = pack_f16(r0.z, r1.z);
      dst[204] = pack_f16(r0.w, r1.w);
    }
#pragma unroll
    for (int u = 0; u < 4; ++u) {
      int ku4 = s_q + 4 * u;
      uint4 v = *(const uint4*)&zh[(size_t)s_kp * 512 + (k0 >> 1) + ku4 * 4];
      *(uint4*)&zl[s_kp * 68 + ku4 * 4] = v;
    }
    __syncthreads();
#pragma unroll
    for (int ks = 0; ks < 4; ++ks) {
      union { uint4 u; f16x8 hh; } bf, a0, a1, a2, a3;
      bf.u = *(const uint4*)&bt[(cw * 16 + c15) * 68 + ks * 16 + kq * 4];
      a0.u = *(const uint4*)&zl[(c15)      * 68 + ks * 16 + kq * 4];
      a1.u = *(const uint4*)&zl[(16 + c15) * 68 + ks * 16 + kq * 4];
      a2.u = *(const uint4*)&zl[(32 + c15) * 68 + ks * 16 + kq * 4];
      a3.u = *(const uint4*)&zl[(48 + c15) * 68 + ks * 16 + kq * 4];
      acc0 = __builtin_amdgcn_mfma_f32_16x16x32_f16(a0.hh, bf.hh, acc0, 0, 0, 0);
      acc1 = __builtin_amdgcn_mfma_f32_16x16x32_f16(a1.hh, bf.hh, acc1, 0, 0, 0);
      acc2 = __builtin_amdgcn_mfma_f32_16x16x32_f16(a2.hh, bf.hh, acc2, 0, 0, 0);
      acc3 = __builtin_amdgcn_mfma_f32_16x16x32_f16(a3.hh, bf.hh, acc3, 0, 0, 0);
    }
  }

  int c = c0 + cw * 16 + c15;
  float* pdst = poseP + (size_t)kh * (NPRI * DPRI * B) + (size_t)c * 64 + kq * 4;
  *(float4*)&pdst[0]  = *(float4*)&acc0;
  *(float4*)&pdst[16] = *(float4*)&acc1;
  *(float4*)&pdst[32] = *(float4*)&acc2;
  *(float4*)&pdst[48] = *(float4*)&acc3;
}

// ---------------- GEMM2 k-split partial ----------------
__global__ __launch_bounds__(256, 2) void k_gemm2p(const float* __restrict__ zn,
                                                   const float* __restrict__ w2,
                                                   float* __restrict__ part) {
  __shared__ __align__(16) float znT[128 * 68];
  __shared__ __align__(16) float wl[128 * 68];
  int t = threadIdx.x;
  int c0 = blockIdx.x * 64;
  int k0 = blockIdx.y * 128;
  int zr_ = t >> 2, za = t & 3;
  int wk = t >> 1, wc = (t & 1) * 32;

#pragma unroll
  for (int jj = 0; jj < 4; ++jj) {
    int kb = za * 8 + jj * 32;
    const float* src = zn + zr_ * DIN + k0 + kb;
    float4 v0 = *(const float4*)src;
    float4 v1 = *(const float4*)(src + 4);
    znT[(kb+0)*68 + zr_] = v0.x; znT[(kb+1)*68 + zr_] = v0.y;
    znT[(kb+2)*68 + zr_] = v0.z; znT[(kb+3)*68 + zr_] = v0.w;
    znT[(kb+4)*68 + zr_] = v1.x; znT[(kb+5)*68 + zr_] = v1.y;
    znT[(kb+6)*68 + zr_] = v1.z; znT[(kb+7)*68 + zr_] = v1.w;
  }
  const float* wsrc = w2 + (size_t)(k0 + wk) * NPRI + c0 + wc;
#pragma unroll
  for (int j = 0; j < 8; ++j)
    *(float4*)&wl[wk * 68 + wc + j * 4] = *(const float4*)(wsrc + j * 4);
  __syncthreads();

  int r0 = (t >> 4) * 4, c0l = (t & 15) * 4;
  float acc[4][4];
#pragma unroll
  for (int j = 0; j < 4; ++j)
#pragma unroll
    for (int i = 0; i < 4; ++i) acc[j][i] = 0.f;

#pragma unroll 4
  for (int k = 0; k < 128; ++k) {
    float4 z4 = *(const float4*)&znT[k * 68 + r0];
    float4 w4 = *(const float4*)&wl[k * 68 + c0l];
    float zz[4] = {z4.x, z4.y, z4.z, z4.w};
    float ww[4] = {w4.x, w4.y, w4.z, w4.w};
#pragma unroll
    for (int j = 0; j < 4; ++j)
#pragma unroll
      for (int i = 0; i < 4; ++i) acc[j][i] += ww[j] * zz[i];
  }
  float* pdst = part + ((size_t)blockIdx.y * NPRI + c0 + c0l) * 64 + r0;
#pragma unroll
  for (int j = 0; j < 4; ++j) {
    float4 o = {acc[j][0], acc[j][1], acc[j][2], acc[j][3]};
    *(float4*)&pdst[j * 64] = o;
  }
}

__global__ __launch_bounds__(256) void k_gemm2r(const float* __restrict__ part,
                                                const float* __restrict__ b2,
                                                float* __restrict__ actt) {
  int idx = blockIdx.x * 256 + threadIdx.x;
  float4 s = {0.f, 0.f, 0.f, 0.f};
#pragma unroll
  for (int kz = 0; kz < KS2; ++kz) {
    float4 v = *(const float4*)&part[(size_t)kz * NPRI * 64 + idx * 4];
    s.x += v.x; s.y += v.y; s.z += v.z; s.w += v.w;
  }
  int c = (idx * 4) >> 6;
  float bc = b2[c];
  float4 o;
  o.x = fminf(fmaxf(1.0f / (1.0f + expf(-(s.x + bc))), 0.0f), 1.0f);
  o.y = fminf(fmaxf(1.0f / (1.0f + expf(-(s.y + bc))), 0.0f), 1.0f);
  o.z = fminf(fmaxf(1.0f / (1.0f + expf(-(s.z + bc))), 0.0f), 1.0f);
  o.w = fminf(fmaxf(1.0f / (1.0f + expf(-(s.w + bc))), 0.0f), 1.0f);
  *(float4*)&actt[idx * 4] = o;
}

// ---------------- votes: V[n][o][b][d] (f16); sums pose k-halves + bias ----------------
__global__ __launch_bounds__(256) void k_votes(const float* __restrict__ poseP,
                                               const float* __restrict__ b1,
                                               const float* __restrict__ wcaps,
                                               unsigned* __restrict__ V) {
  __shared__ __align__(16) float wl[6400];
  __shared__ __align__(16) float pl[64 * 16];
  int n = blockIdx.x, t = threadIdx.x;
  const float* wsrc = wcaps + (size_t)n * 6400;
  for (int idx = t * 4; idx < 6400; idx += 1024)
    *(float4*)(wl + idx) = *(const float4*)(wsrc + idx);
  {
    float4 v0 = *(const float4*)(poseP + n * 1024 + t * 4);
    float4 v1 = *(const float4*)(poseP + (NPRI * DPRI * B) + n * 1024 + t * 4);
    int i = t >> 4, b = (t & 15) * 4;
    float bc_ = b1[n * 16 + i];
    pl[(b+0)*16 + i] = v0.x + v1.x + bc_;
    pl[(b+1)*16 + i] = v0.y + v1.y + bc_;
    pl[(b+2)*16 + i] = v0.z + v1.z + bc_;
    pl[(b+3)*16 + i] = v0.w + v1.w + bc_;
  }
  __syncthreads();
  if (t >= 200) return;
  int o = t / 8, d0 = (t % 8) * 2;
  float w0[16], w1_[16];
#pragma unroll
  for (int i = 0; i < 16; ++i) {
    w0[i]  = wl[(i * 25 + o) * 16 + d0];
    w1_[i] = wl[(i * 25 + o) * 16 + d0 + 1];
  }
  unsigned* vd = V + (((size_t)n * 25 + o) * 64 * 16 + d0) / 2;
  for (int b = 0; b < 64; ++b) {
    const float* pb = &pl[b * 16];
    float a0 = 0.f, a1 = 0.f;
#pragma unroll
    for (int i = 0; i < 16; ++i) {
      float p = pb[i];
      a0 += p * w0[i];
      a1 += p * w1_[i];
    }
    vd[b * 8] = pack_f16(a0, a1);
  }
}

// ---------------- M-step moment accumulation (V f16, R f16) ----------------
template <bool UNIFORM>
__global__ __launch_bounds__(256) void k_stats(const unsigned* __restrict__ V,
                                               const float* __restrict__ actt,
                                               const unsigned short* __restrict__ Rh,
                                               float* __restrict__ part) {
  int o = blockIdx.y;
  int t = threadIdx.x, b = t & 63, wv = t >> 6;
  float S0 = 0.f, S1[16], S2[16];
#pragma unroll
  for (int d = 0; d < 16; ++d) { S1[d] = 0.f; S2[d] = 0.f; }
  int n0 = blockIdx.x * 128 + wv * 32;
  for (int k = 0; k < 32; ++k) {
    int n = n0 + k;
    float a = actt[n * 64 + b];
    float r = UNIFORM ? a * (1.0f / 25.0f)
                      : f16val(Rh[((size_t)n * 25 + o) * 64 + b]) * a;
    const uint4* vp = (const uint4*)(V + (((size_t)n * 25 + o) * 64 + b) * 8);
    uint4 u0 = vp[0], u1 = vp[1];
    unsigned uu[8] = {u0.x, u0.y, u0.z, u0.w, u1.x, u1.y, u1.z, u1.w};
    S0 += r;
#pragma unroll
    for (int q = 0; q < 8; ++q) {
      float v0 = f16lo(uu[q]), v1 = f16hi(uu[q]);
      float t0 = r * v0, t1 = r * v1;
      S1[2*q]   += t0;          S1[2*q+1] += t1;
      S2[2*q]   += t0 * v0;     S2[2*q+1] += t1 * v1;
    }
  }
  __shared__ float red[4 * 33 * 64];
  red[(wv * 33 + 0) * 64 + b] = S0;
#pragma unroll
  for (int d = 0; d < 16; ++d) {
    red[(wv * 33 + 1 + d) * 64 + b]  = S1[d];
    red[(wv * 33 + 17 + d) * 64 + b] = S2[d];
  }
  __syncthreads();
  if (wv == 0) {
    for (int s = 0; s < 33; ++s) {
      float tot = red[s * 64 + b] + red[(33 + s) * 64 + b] +
                  red[(66 + s) * 64 + b] + red[(99 + s) * 64 + b];
      part[((o * NCH + blockIdx.x) * 33 + s) * 64 + b] = tot;
    }
  }
}

// ---------------- merged reduce + finish (+ optional final outputs) ----------------
template <bool FINAL>
__global__ __launch_bounds__(256) void k_redfin(const float* __restrict__ part,
                                                const float* __restrict__ beta_u,
                                                const float* __restrict__ beta_a,
                                                float* __restrict__ mi4,
                                                float* __restrict__ basew,
                                                const float* __restrict__ g2,
                                                const float* __restrict__ bb2,
                                                const float* __restrict__ w3,
                                                const float* __restrict__ b3,
                                                float* __restrict__ out) {
  __shared__ float st[33 * 64];
  int o = blockIdx.x, t = threadIdx.x;
  for (int slot = t; slot < 33 * 64; slot += 256) {
    float s = 0.f;
    const float* pp = part + (size_t)o * NCH * 2112 + slot;
#pragma unroll
    for (int c = 0; c < NCH; ++c) s += pp[(size_t)c * 2112];
    st[slot] = s;
  }
  __syncthreads();
  if (t < 64) {
    int b = t;
    float s0 = st[b];
    float rsm = s0 + EMEPS;
    float inv_rs = 1.0f / rsm;
    float ldet = 0.f;
    float mloc[16], iloc[16];
#pragma unroll
    for (int d = 0; d < 16; ++d) {
      float s1 = st[(1 + d) * 64 + b];
      float s2 = st[(17 + d) * 64 + b];
      float m = s1 * inv_rs;
      float var = (s2 - 2.0f * m * s1 + m * m * s0) * inv_rs;
      float sg = fmaxf(var, 0.0f) + EMEPS;
      mloc[d] = m;
      iloc[d] = 1.0f / sg;
      ldet += logf(sg);
    }
#pragma unroll
    for (int q = 0; q < 8; ++q) {
      float4 v = {mloc[2*q], iloc[2*q], mloc[2*q+1], iloc[2*q+1]};
      *(float4*)&mi4[((o * 8 + q) * 64 + b) * 4] = v;
    }
    float cost = (16.0f * beta_u[o] + 0.5f * ldet) * rsm;
    float x = beta_a[o] - cost;
    float a = 1.0f / (1.0f + expf(-x));
    basew[o * 64 + b] = logf(a + EMEPS) - 0.5f * ldet;

    if (FINAL) {
      float sm = 0.f;
#pragma unroll
      for (int d = 0; d < 16; ++d) sm += mloc[d];
      float mean = sm * (1.0f / 16.0f);
      float var2 = 0.f;
#pragma unroll
      for (int d = 0; d < 16; ++d) { float dd = mloc[d] - mean; var2 += dd * dd; }
      var2 *= (1.0f / 16.0f);
      float inv2 = 1.0f / sqrtf(var2 + LNEPS);
      float logit = 0.f, nrm = 0.f;
#pragma unroll
      for (int d = 0; d < 16; ++d) {
        float nh = (mloc[d] - mean) * inv2 * g2[d] + bb2[d];
        logit += nh * w3[d];
        nrm += mloc[d] * mloc[d];
      }
      out[b * 25 + o] = logit + b3[0];
      out[1600 + b * 25 + o] = sqrtf(nrm);
      float* pp = out + 3200 + (b * 25 + o) * 16;
#pragma unroll
      for (int d = 0; d < 16; ++d) pp[d] = mloc[d];
    }
  }
}

// ---------------- fused E-step: logp + softmax -> R (f16) or q ----------------
template <bool FINAL>
__global__ __launch_bounds__(256) void k_estep(const unsigned* __restrict__ V,
                                               const float* __restrict__ mi4,
                                               const float* __restrict__ basew,
                                               unsigned short* __restrict__ Rh,
                                               float* __restrict__ qout) {
  int t = threadIdx.x, b = t & 63, ng = t >> 6;
  int n = blockIdx.x * 4 + ng;
  float l[25];
  float mx = -1e30f;
#pragma unroll
  for (int o = 0; o < 25; ++o) {
    const uint4* vp = (const uint4*)(V + (((size_t)n * 25 + o) * 64 + b) * 8);
    uint4 u0 = vp[0], u1 = vp[1];
    unsigned uu[8] = {u0.x, u0.y, u0.z, u0.w, u1.x, u1.y, u1.z, u1.w};
    float acc = 0.f;
#pragma unroll
    for (int qq = 0; qq < 8; ++qq) {
      float4 mi = *(const float4*)&mi4[((o * 8 + qq) * 64 + b) * 4];
      float d0 = f16lo(uu[qq]) - mi.x;
      float d1 = f16hi(uu[qq]) - mi.z;
      acc += d0 * d0 * mi.y + d1 * d1 * mi.w;
    }
    l[o] = basew[o * 64 + b] - 0.5f * acc;
    mx = fmaxf(mx, l[o]);
  }
  float s = 0.f;
#pragma unroll
  for (int o = 0; o < 25; ++o) { l[o] = expf(l[o] - mx); s += l[o]; }
  float inv = 1.0f / s;
  if (FINAL) {
    float* qp = qout + ((size_t)b * NPRI + n) * 25;
#pragma unroll
    for (int o = 0; o < 25; ++o) qp[o] = l[o] * inv;
  } else {
#pragma unroll
    for (int o = 0; o < 25; ++o)
      Rh[((size_t)n * 25 + o) * 64 + b] = f16bits(l[o] * inv);
  }
}

extern "C" void kernel_launch(void* const* d_in, const int* in_sizes, int n_in,
                              void* d_out, int out_size, void* d_ws, size_t ws_size,
                              hipStream_t stream) {
  const float* z      = (const float*)d_in[0];
  const float* w1     = (const float*)d_in[1];
  const float* b1     = (const float*)d_in[2];
  const float* ln1g   = (const float*)d_in[3];
  const float* ln1b   = (const float*)d_in[4];
  const float* w2     = (const float*)d_in[5];
  const float* b2     = (const float*)d_in[6];
  const float* wcaps  = (const float*)d_in[7];
  const float* beta_u = (const float*)d_in[8];
  const float* beta_a = (const float*)d_in[9];
  const float* ln2g   = (const float*)d_in[10];
  const float* ln2b   = (const float*)d_in[11];
  const float* w3     = (const float*)d_in[12];
  const float* b3     = (const float*)d_in[13];

  if (ws_size < (size_t)WS_FLOATS * 4) {
    fprintf(stderr, "kernel_launch: ws too small: %zu < %zu bytes\n",
            ws_size, (size_t)WS_FLOATS * 4);
  }

  float* ws    = (float*)d_ws;
  float* out   = (float*)d_out;
  float* poseP = ws + OFF_POSE;
  float* zn    = ws + OFF_ZN;
  float* actt  = ws + OFF_ACTT;
  float* g2p   = ws + OFF_G2P;
  unsigned* V  = (unsigned*)(ws + OFF_V);
  unsigned short* Rh = (unsigned short*)(ws + OFF_R);
  float* part  = ws + OFF_PART;
  float* mi4   = ws + OFF_MI4;
  float* bse   = ws + OFF_BASE;
  unsigned* zh = (unsigned*)(ws + OFF_ZH);

  k_lnzh<<<64, 256, 0, stream>>>(z, ln1g, ln1b, zn, zh);
  k_gemm1m<<<dim3(512, 2), 256, 0, stream>>>(zh, w1, poseP);
  k_gemm2p<<<dim3(32, KS2), 256, 0, stream>>>(zn, w2, g2p);
  k_gemm2r<<<128, 256, 0, stream>>>(g2p, b2, actt);
  k_votes<<<2048, 256, 0, stream>>>(poseP, b1, wcaps, V);

  // iteration 1 (uniform R)
  k_stats<true><<<dim3(NCH, 25), 256, 0, stream>>>(V, actt, Rh, part);
  k_redfin<false><<<25, 256, 0, stream>>>(part, beta_u, beta_a, mi4, bse,
                                          ln2g, ln2b, w3, b3, out);

  // iteration 2
  k_estep<false><<<512, 256, 0, stream>>>(V, mi4, bse, Rh, nullptr);
  k_stats<false><<<dim3(NCH, 25), 256, 0, stream>>>(V, actt, Rh, part);
  k_redfin<false><<<25, 256, 0, stream>>>(part, beta_u, beta_a, mi4, bse,
                                          ln2g, ln2b, w3, b3, out);

  // iteration 3 (final M-step also writes logits/acts/pose)
  k_estep<false><<<512, 256, 0, stream>>>(V, mi4, bse, Rh, nullptr);
  k_stats<false><<<dim3(NCH, 25), 256, 0, stream>>>(V, actt, Rh, part);
  k_redfin<true><<<25, 256, 0, stream>>>(part, beta_u, beta_a, mi4, bse,
                                         ln2g, ln2b, w3, b3, out);

  // final E-step -> q
  k_estep<true><<<512, 256, 0, stream>>>(V, mi4, bse, nullptr, out + 28800);
}